// Round 1
// baseline (918.153 us; speedup 1.0000x reference)
//
#include <hip/hip_runtime.h>
#include <cstdint>
#include <cstddef>

typedef __bf16 bf16x8 __attribute__((ext_vector_type(8)));
typedef float  f32x4  __attribute__((ext_vector_type(4)));
typedef unsigned short u16;

__device__ __forceinline__ u16 f2bf(float f) {
  unsigned int u = __builtin_bit_cast(unsigned int, f);
  u += 0x7fffu + ((u >> 16) & 1u);
  return (u16)(u >> 16);
}

__device__ __forceinline__ void load_lds16(const void* g, void* l) {
  __builtin_amdgcn_global_load_lds((const __attribute__((address_space(1))) void*)g,
                                   (__attribute__((address_space(3))) void*)l,
                                   16, 0, 0);
}

// ---------------- elementwise f32 -> bf16 cast ----------------
__global__ __launch_bounds__(256) void cast_f2b(const float* __restrict__ in,
                                                u16* __restrict__ out, int n4) {
  int idx = blockIdx.x * 256 + threadIdx.x;
  const int stride = gridDim.x * 256;
  for (; idx < n4; idx += stride) {
    float4 v = ((const float4*)in)[idx];
    uint2 pk;
    pk.x = (unsigned)f2bf(v.x) | ((unsigned)f2bf(v.y) << 16);
    pk.y = (unsigned)f2bf(v.z) | ((unsigned)f2bf(v.w) << 16);
    ((uint2*)out)[idx] = pk;
  }
}

// ---------------- tiled transpose + cast: in (R x C) f32 -> out (C x R) bf16 ----
__global__ void transpose_cast(const float* __restrict__ in, u16* __restrict__ out,
                               int R, int C) {
  __shared__ float tile[32][33];
  const int tx = threadIdx.x, ty = threadIdx.y;
  const long c0 = (long)blockIdx.x * 32, r0 = (long)blockIdx.y * 32;
#pragma unroll
  for (int i = 0; i < 4; i++)
    tile[ty + i * 8][tx] = in[(r0 + ty + i * 8) * (long)C + c0 + tx];
  __syncthreads();
#pragma unroll
  for (int i = 0; i < 4; i++)
    out[(c0 + ty + i * 8) * (long)R + r0 + tx] = f2bf(tile[tx][ty + i * 8]);
}

// ---------------- m97-structure bf16 GEMM: C[M,N] = A[M,K] * Bt[N,K]^T --------
// 128x128 tile, BK=32, 256 thr = 4 waves (2x2), each wave 64x64 (4x4 frags).
template <int BF16_OUT>
__global__ __launch_bounds__(256) void gemm_bt(const u16* __restrict__ A,
                                               const u16* __restrict__ Bt,
                                               void* __restrict__ Cv,
                                               int M, int N, int K) {
  __shared__ u16 As[128 * 32];
  __shared__ u16 Bs[128 * 32];
  const int tid = threadIdx.x;
  const int lane = tid & 63;
  const int g = lane >> 4, r16 = lane & 15;
  const int wid = tid >> 6;
  const int wr = wid >> 1, wc = wid & 1;
  const long bm = (long)blockIdx.y * 128, bn = (long)blockIdx.x * 128;

  const u16* gA = A + (bm + (tid >> 2)) * (long)K + (tid & 3) * 8;
  const u16* gB = Bt + (bn + (tid >> 2)) * (long)K + (tid & 3) * 8;
  u16* lA = As + tid * 8;
  u16* lB = Bs + tid * 8;

  f32x4 acc[4][4];
#pragma unroll
  for (int m = 0; m < 4; m++)
#pragma unroll
    for (int n = 0; n < 4; n++)
#pragma unroll
      for (int j = 0; j < 4; j++) acc[m][n][j] = 0.f;

  for (int k0 = 0; k0 < K; k0 += 32) {
    load_lds16(gA + k0, lA);
    load_lds16(gA + 64 * (long)K + k0, lA + 256 * 8);
    load_lds16(gB + k0, lB);
    load_lds16(gB + 64 * (long)K + k0, lB + 256 * 8);
    __syncthreads();  // drains vmcnt: staging visible
    bf16x8 af[4], bfr[4];
#pragma unroll
    for (int m = 0; m < 4; m++)
      af[m] = *(const bf16x8*)(As + (wr * 64 + m * 16 + r16) * 32 + g * 8);
#pragma unroll
    for (int n = 0; n < 4; n++)
      bfr[n] = *(const bf16x8*)(Bs + (wc * 64 + n * 16 + r16) * 32 + g * 8);
#pragma unroll
    for (int m = 0; m < 4; m++)
#pragma unroll
      for (int n = 0; n < 4; n++)
        acc[m][n] = __builtin_amdgcn_mfma_f32_16x16x32_bf16(af[m], bfr[n], acc[m][n], 0, 0, 0);
    __syncthreads();  // compute done before next stage overwrites
  }

  const long crow = bm + wr * 64 + g * 4;
  const long ccol = bn + wc * 64 + r16;
  if (BF16_OUT) {
    u16* C = (u16*)Cv;
#pragma unroll
    for (int m = 0; m < 4; m++)
#pragma unroll
      for (int n = 0; n < 4; n++)
#pragma unroll
        for (int j = 0; j < 4; j++)
          C[(crow + m * 16 + j) * (long)N + ccol + n * 16] = f2bf(acc[m][n][j]);
  } else {
    float* C = (float*)Cv;
#pragma unroll
    for (int m = 0; m < 4; m++)
#pragma unroll
      for (int n = 0; n < 4; n++)
#pragma unroll
        for (int j = 0; j < 4; j++)
          C[(crow + m * 16 + j) * (long)N + ccol + n * 16] = acc[m][n][j];
  }
}

// ---------------- causal GQA flash attention ----------------
// grid (S/64, NH, B), 256 thr = 4 waves; wave w owns 16 Q rows.
// Swapped QK^T: S^T = mfma(K, Q) so per-lane q = lane&15 (row-local softmax).
// K tile [64][128] and V^T tile [128][64] staged with chunk-XOR swizzle via
// pre-swizzled global source + linear global_load_lds dest (rule #21).
#define SCALE_F 0.08838834764831845f

__global__ __launch_bounds__(256) void attn_fwd(const u16* __restrict__ Q,
                                                const u16* __restrict__ Kg,
                                                const u16* __restrict__ VT,
                                                u16* __restrict__ Og) {
  __shared__ u16 Ks[64 * 128];
  __shared__ u16 Vs[128 * 64];
  __shared__ u16 Ps[4 * 16 * 64];
  const int tid = threadIdx.x;
  const int lane = tid & 63;
  const int w = tid >> 6;
  const int g = lane >> 4, r16 = lane & 15;
  const int qt = blockIdx.x, h = blockIdx.y, b = blockIdx.z;
  const int kvh = h >> 2;        // NREP = 4
  const int qbase = qt * 64;
  const int qrow = qbase + w * 16 + r16;

  // hoist Q B-fragments: lane holds Q[qrow][kc*32 + g*8 + j]
  bf16x8 qf[4];
  {
    const u16* qp = Q + ((long)(b * 2048 + qrow)) * 4096 + h * 128 + g * 8;
#pragma unroll
    for (int kc = 0; kc < 4; kc++) qf[kc] = *(const bf16x8*)(qp + kc * 32);
  }

  f32x4 oacc[8];
#pragma unroll
  for (int dt = 0; dt < 8; dt++)
#pragma unroll
    for (int j = 0; j < 4; j++) oacc[dt][j] = 0.f;
  float mrun = -__builtin_inff(), lrun = 0.f;

  const u16* kb_ptr = Kg + ((long)b * 2048) * 1024 + kvh * 128;
  const u16* vb_ptr = VT + ((long)kvh * 128) * 4096 + (long)b * 2048;
  u16* pw = Ps + w * (16 * 64);

  for (int kt = 0; kt <= qt; kt++) {
    const int kb = kt * 64;
    // ---- stage K (64x128) and V^T (128x64), chunk-swizzled ----
#pragma unroll
    for (int i = 0; i < 4; i++) {
      int slot = i * 256 + tid;
      int r = slot >> 4, cs = slot & 15;
      int ck = (cs & 8) | ((cs ^ r) & 7);
      load_lds16(kb_ptr + (long)(kb + r) * 1024 + ck * 8, Ks + slot * 8);
      int d = slot >> 3, c8 = slot & 7;
      int cv = (c8 ^ d) & 7;
      load_lds16(vb_ptr + (long)d * 4096 + kb + cv * 8, Vs + slot * 8);
    }
    __syncthreads();

    // ---- QK^T: S^T[kv][q], 4 kv-subtiles x 4 d-chunks ----
    f32x4 st[4];
#pragma unroll
    for (int t = 0; t < 4; t++)
#pragma unroll
      for (int j = 0; j < 4; j++) st[t][j] = 0.f;
#pragma unroll
    for (int t = 0; t < 4; t++) {
      const int r = t * 16 + r16;
#pragma unroll
      for (int kc = 0; kc < 4; kc++) {
        int c = kc * 4 + g;
        int cz = (c & 8) | ((c ^ r) & 7);
        bf16x8 kf = *(const bf16x8*)(Ks + r * 128 + cz * 8);
        st[t] = __builtin_amdgcn_mfma_f32_16x16x32_bf16(kf, qf[kc], st[t], 0, 0, 0);
      }
    }
    // ---- online softmax (per-lane row q = r16; kv = kb + t*16 + g*4 + j) ----
    float p[4][4];
    float tmax = -__builtin_inff();
#pragma unroll
    for (int t = 0; t < 4; t++)
#pragma unroll
      for (int j = 0; j < 4; j++) {
        float s = st[t][j] * SCALE_F;
        int kv = kb + t * 16 + g * 4 + j;
        s = (kv > qrow) ? -__builtin_inff() : s;
        p[t][j] = s;
        tmax = fmaxf(tmax, s);
      }
    tmax = fmaxf(tmax, __shfl_xor(tmax, 16));
    tmax = fmaxf(tmax, __shfl_xor(tmax, 32));
    const float mnew = fmaxf(mrun, tmax);
    const float escale = __expf(mrun - mnew);
    float psum = 0.f;
#pragma unroll
    for (int t = 0; t < 4; t++)
#pragma unroll
      for (int j = 0; j < 4; j++) {
        float e = __expf(p[t][j] - mnew);
        p[t][j] = e;
        psum += e;
      }
    psum += __shfl_xor(psum, 16);
    psum += __shfl_xor(psum, 32);
    lrun = lrun * escale + psum;
    mrun = mnew;

    // ---- write P (bf16) to per-wave LDS, row-XOR-swizzled 128B rows ----
#pragma unroll
    for (int t = 0; t < 4; t++)
#pragma unroll
      for (int pp = 0; pp < 2; pp++) {
        int kvl = t * 16 + g * 4 + pp * 2;
        unsigned int val = (unsigned)f2bf(p[t][pp * 2]) | ((unsigned)f2bf(p[t][pp * 2 + 1]) << 16);
        int off = r16 * 128 + ((kvl * 2) ^ ((r16 & 7) << 4));
        *(unsigned int*)((char*)pw + off) = val;
      }

    // ---- rescale O (O layout: q = g*4 + j, d = dt*16 + r16) ----
    float es[4];
#pragma unroll
    for (int j = 0; j < 4; j++) es[j] = __shfl(escale, (lane & 48) + g * 4 + j);
#pragma unroll
    for (int dt = 0; dt < 8; dt++)
#pragma unroll
      for (int j = 0; j < 4; j++) oacc[dt][j] *= es[j];

    // ---- PV: O += P * V ----
#pragma unroll
    for (int kc2 = 0; kc2 < 2; kc2++) {
      int c = kc2 * 4 + g;
      int cp = c ^ (r16 & 7);
      bf16x8 pa = *(const bf16x8*)(pw + r16 * 64 + cp * 8);
#pragma unroll
      for (int dt = 0; dt < 8; dt++) {
        int d = dt * 16 + r16;
        int cz = c ^ (d & 7);
        bf16x8 vf = *(const bf16x8*)(Vs + d * 64 + cz * 8);
        oacc[dt] = __builtin_amdgcn_mfma_f32_16x16x32_bf16(pa, vf, oacc[dt], 0, 0, 0);
      }
    }
    __syncthreads();
  }

  // ---- normalize + store ----
  float li[4];
#pragma unroll
  for (int j = 0; j < 4; j++)
    li[j] = 1.f / __shfl(lrun, (lane & 48) + g * 4 + j);
  u16* op = Og + ((long)(b * 2048 + qbase + w * 16 + g * 4)) * 4096 + h * 128 + r16;
#pragma unroll
  for (int dt = 0; dt < 8; dt++)
#pragma unroll
    for (int j = 0; j < 4; j++)
      op[(long)j * 4096 + dt * 16] = f2bf(oacc[dt][j] * li[j]);
}

// ---------------- launch ----------------
extern "C" void kernel_launch(void* const* d_in, const int* in_sizes, int n_in,
                              void* d_out, int out_size, void* d_ws, size_t ws_size,
                              hipStream_t stream) {
  (void)in_sizes; (void)n_in; (void)out_size; (void)ws_size;
  const float* x  = (const float*)d_in[0];
  const float* wq = (const float*)d_in[1];
  const float* wk = (const float*)d_in[2];
  const float* wv = (const float*)d_in[3];
  const float* wo = (const float*)d_in[4];
  float* out = (float*)d_out;

  u16* xb   = (u16*)d_ws;                       // 4096x4096 bf16 (x)
  u16* wqT  = xb  + (size_t)4096 * 4096;        // 4096x4096 (N,K)
  u16* wkT  = wqT + (size_t)4096 * 4096;        // 1024x4096
  u16* wvT  = wkT + (size_t)1024 * 4096;        // 1024x4096
  u16* woT  = wvT + (size_t)1024 * 4096;        // 4096x4096
  u16* qb   = woT + (size_t)4096 * 4096;        // 4096x4096 (B*S, NH*HD)
  u16* kbuf = qb  + (size_t)4096 * 4096;        // 4096x1024 (B*S, NKV*HD)
  u16* vT   = kbuf + (size_t)4096 * 1024;       // 1024x4096 (NKV*HD, B*S)
  u16* attn = vT  + (size_t)1024 * 4096;        // 4096x4096

  cast_f2b<<<2048, 256, 0, stream>>>(x, xb, 4096 * 4096 / 4);
  transpose_cast<<<dim3(128, 128), dim3(32, 8), 0, stream>>>(wq, wqT, 4096, 4096);
  transpose_cast<<<dim3(32, 128),  dim3(32, 8), 0, stream>>>(wk, wkT, 4096, 1024);
  transpose_cast<<<dim3(32, 128),  dim3(32, 8), 0, stream>>>(wv, wvT, 4096, 1024);
  transpose_cast<<<dim3(128, 128), dim3(32, 8), 0, stream>>>(wo, woT, 4096, 4096);

  // q = x @ wq ; k = x @ wk ; vT = (x @ wv)^T  (computed directly as wvT * xb^T)
  gemm_bt<1><<<dim3(32, 32), 256, 0, stream>>>(xb, wqT, qb, 4096, 4096, 4096);
  gemm_bt<1><<<dim3(8, 32),  256, 0, stream>>>(xb, wkT, kbuf, 4096, 1024, 4096);
  gemm_bt<1><<<dim3(32, 8),  256, 0, stream>>>(wvT, xb, vT, 1024, 4096, 4096);

  attn_fwd<<<dim3(32, 32, 2), 256, 0, stream>>>(qb, kbuf, vT, attn);

  gemm_bt<0><<<dim3(32, 32), 256, 0, stream>>>(attn, woT, out, 4096, 4096, 4096);
}

// Round 2
// 847.154 us; speedup vs baseline: 1.0838x; 1.0838x over previous
//
#include <hip/hip_runtime.h>
#include <cstdint>
#include <cstddef>

typedef __bf16 bf16x8 __attribute__((ext_vector_type(8)));
typedef float  f32x4  __attribute__((ext_vector_type(4)));
typedef unsigned short u16;

#define SCALE_F 0.08838834764831845f

__device__ __forceinline__ u16 f2bf(float f) {
  unsigned int u = __builtin_bit_cast(unsigned int, f);
  u += 0x7fffu + ((u >> 16) & 1u);
  return (u16)(u >> 16);
}

__device__ __forceinline__ void load_lds16(const void* g, void* l) {
  __builtin_amdgcn_global_load_lds((const __attribute__((address_space(1))) void*)g,
                                   (__attribute__((address_space(3))) void*)l,
                                   16, 0, 0);
}

// ---------------- elementwise f32 -> bf16 cast ----------------
__global__ __launch_bounds__(256) void cast_f2b(const float* __restrict__ in,
                                                u16* __restrict__ out, int n4) {
  int idx = blockIdx.x * 256 + threadIdx.x;
  const int stride = gridDim.x * 256;
  for (; idx < n4; idx += stride) {
    float4 v = ((const float4*)in)[idx];
    uint2 pk;
    pk.x = (unsigned)f2bf(v.x) | ((unsigned)f2bf(v.y) << 16);
    pk.y = (unsigned)f2bf(v.z) | ((unsigned)f2bf(v.w) << 16);
    ((uint2*)out)[idx] = pk;
  }
}

// ------- tiled transpose + cast + scale: in (R x C) f32 -> out (C x R) bf16 ----
__global__ void transpose_cast(const float* __restrict__ in, u16* __restrict__ out,
                               int R, int C, float scale) {
  __shared__ float tile[32][33];
  const int tx = threadIdx.x, ty = threadIdx.y;
  const long c0 = (long)blockIdx.x * 32, r0 = (long)blockIdx.y * 32;
#pragma unroll
  for (int i = 0; i < 4; i++)
    tile[ty + i * 8][tx] = in[(r0 + ty + i * 8) * (long)C + c0 + tx];
  __syncthreads();
#pragma unroll
  for (int i = 0; i < 4; i++)
    out[(c0 + ty + i * 8) * (long)R + r0 + tx] = f2bf(tile[tx][ty + i * 8] * scale);
}

// ---------------- m97-structure bf16 GEMM: C[M,N] = A[M,K] * Bt[N,K]^T --------
// 128x128 tile, BK=32, 256 thr = 4 waves (2x2), each wave 64x64 (4x4 frags).
template <int BF16_OUT>
__global__ __launch_bounds__(256) void gemm_bt(const u16* __restrict__ A,
                                               const u16* __restrict__ Bt,
                                               void* __restrict__ Cv,
                                               int M, int N, int K) {
  __shared__ u16 As[128 * 32];
  __shared__ u16 Bs[128 * 32];
  const int tid = threadIdx.x;
  const int lane = tid & 63;
  const int g = lane >> 4, r16 = lane & 15;
  const int wid = tid >> 6;
  const int wr = wid >> 1, wc = wid & 1;
  const long bm = (long)blockIdx.y * 128, bn = (long)blockIdx.x * 128;

  const u16* gA = A + (bm + (tid >> 2)) * (long)K + (tid & 3) * 8;
  const u16* gB = Bt + (bn + (tid >> 2)) * (long)K + (tid & 3) * 8;
  u16* lA = As + tid * 8;
  u16* lB = Bs + tid * 8;

  f32x4 acc[4][4];
#pragma unroll
  for (int m = 0; m < 4; m++)
#pragma unroll
    for (int n = 0; n < 4; n++)
#pragma unroll
      for (int j = 0; j < 4; j++) acc[m][n][j] = 0.f;

  for (int k0 = 0; k0 < K; k0 += 32) {
    load_lds16(gA + k0, lA);
    load_lds16(gA + 64 * (long)K + k0, lA + 256 * 8);
    load_lds16(gB + k0, lB);
    load_lds16(gB + 64 * (long)K + k0, lB + 256 * 8);
    __syncthreads();  // drains vmcnt: staging visible
    bf16x8 af[4], bfr[4];
#pragma unroll
    for (int m = 0; m < 4; m++)
      af[m] = *(const bf16x8*)(As + (wr * 64 + m * 16 + r16) * 32 + g * 8);
#pragma unroll
    for (int n = 0; n < 4; n++)
      bfr[n] = *(const bf16x8*)(Bs + (wc * 64 + n * 16 + r16) * 32 + g * 8);
#pragma unroll
    for (int m = 0; m < 4; m++)
#pragma unroll
      for (int n = 0; n < 4; n++)
        acc[m][n] = __builtin_amdgcn_mfma_f32_16x16x32_bf16(af[m], bfr[n], acc[m][n], 0, 0, 0);
    __syncthreads();  // compute done before next stage overwrites
  }

  const long crow = bm + wr * 64 + g * 4;
  const long ccol = bn + wc * 64 + r16;
  if (BF16_OUT) {
    u16* C = (u16*)Cv;
#pragma unroll
    for (int m = 0; m < 4; m++)
#pragma unroll
      for (int n = 0; n < 4; n++)
#pragma unroll
        for (int j = 0; j < 4; j++)
          C[(crow + m * 16 + j) * (long)N + ccol + n * 16] = f2bf(acc[m][n][j]);
  } else {
    float* C = (float*)Cv;
#pragma unroll
    for (int m = 0; m < 4; m++)
#pragma unroll
      for (int n = 0; n < 4; n++)
#pragma unroll
        for (int j = 0; j < 4; j++)
          C[(crow + m * 16 + j) * (long)N + ccol + n * 16] = acc[m][n][j];
  }
}

// ---------------- causal GQA flash attention (v2) ----------------
// grid (S/128, NH, B), 512 thr = 8 waves; wave w owns 16 Q rows.
// 2-phase double-buffered K/V staging (prefetch tile kt+1 during compute of kt).
// Swapped QK^T: S^T = mfma(K, Q), per-lane q = lane&15 (row-local softmax).
// Q pre-scaled by SCALE_F at projection time. Defer-max (THR=8). Wave-level
// skip of fully-masked tiles; mask only on diagonal-intersecting tiles.
__global__ __launch_bounds__(512, 4) void attn_fwd(const u16* __restrict__ Q,
                                                   const u16* __restrict__ Kg,
                                                   const u16* __restrict__ VT,
                                                   u16* __restrict__ Og) {
  __shared__ u16 Ks[2][64 * 128];
  __shared__ u16 Vs[2][128 * 64];
  __shared__ u16 Ps[8][16 * 64];
  const int tid = threadIdx.x;
  const int lane = tid & 63;
  const int w = tid >> 6;
  const int g = lane >> 4, r16 = lane & 15;
  const int qt = blockIdx.x, h = blockIdx.y, b = blockIdx.z;
  const int kvh = h >> 2;        // NREP = 4
  const int qbase = qt * 128;
  const int qlo = qbase + w * 16;    // wave's lowest q row
  const int qrow = qlo + r16;

  // hoist Q B-fragments: lane holds Q[qrow][kc*32 + g*8 + j] (pre-scaled)
  bf16x8 qf[4];
  {
    const u16* qp = Q + ((long)(b * 2048 + qrow)) * 4096 + h * 128 + g * 8;
#pragma unroll
    for (int kc = 0; kc < 4; kc++) qf[kc] = *(const bf16x8*)(qp + kc * 32);
  }

  f32x4 oacc[8];
#pragma unroll
  for (int dt = 0; dt < 8; dt++)
#pragma unroll
    for (int j = 0; j < 4; j++) oacc[dt][j] = 0.f;
  float mrun = -__builtin_inff(), lrun = 0.f;

  const u16* kb_ptr = Kg + ((long)b * 2048) * 1024 + kvh * 128;
  const u16* vb_ptr = VT + ((long)kvh * 128) * 4096 + (long)b * 2048;
  u16* pw = Ps[w];

  const int nkt = 2 * (qt + 1);

  // stage K (64x128) and V^T (128x64) into buffer bf, chunk-XOR pre-swizzled
  // global source + linear global_load_lds dest (rule #21).
  auto stage = [&](int bf, int kb) {
#pragma unroll
    for (int i = 0; i < 2; i++) {
      int slot = i * 512 + tid;
      int r = slot >> 4, cs = slot & 15;
      int ck = (cs & 8) | ((cs ^ r) & 7);
      load_lds16(kb_ptr + (long)(kb + r) * 1024 + ck * 8, &Ks[bf][slot * 8]);
      int d = slot >> 3, c8 = slot & 7;
      int cv = (c8 ^ d) & 7;
      load_lds16(vb_ptr + (long)d * 4096 + kb + cv * 8, &Vs[bf][slot * 8]);
    }
  };

  stage(0, 0);
  __syncthreads();  // vmcnt drained by compiler before barrier
  int cur = 0;

  for (int kt = 0; kt < nkt; kt++) {
    const int kb = kt * 64;
    if (kt + 1 < nkt) stage(cur ^ 1, kb + 64);  // prefetch overlaps compute

    if (kb <= qlo + 15) {  // wave-uniform: skip fully-masked tiles
      const bool masked = (kb + 63 > qlo);

      // ---- QK^T: S^T[kv][q], 4 kv-subtiles x 4 d-chunks ----
      f32x4 st[4];
#pragma unroll
      for (int t = 0; t < 4; t++)
#pragma unroll
        for (int j = 0; j < 4; j++) st[t][j] = 0.f;
#pragma unroll
      for (int t = 0; t < 4; t++) {
        const int r = t * 16 + r16;
#pragma unroll
        for (int kc = 0; kc < 4; kc++) {
          int c = kc * 4 + g;
          int cz = (c & 8) | ((c ^ r) & 7);
          bf16x8 kf = *(const bf16x8*)(&Ks[cur][r * 128 + cz * 8]);
          st[t] = __builtin_amdgcn_mfma_f32_16x16x32_bf16(kf, qf[kc], st[t], 0, 0, 0);
        }
      }

      // ---- online softmax (per-lane row q = r16; kv = kb + t*16 + g*4 + j) ----
      float p[4][4];
      float tmax = -__builtin_inff();
#pragma unroll
      for (int t = 0; t < 4; t++)
#pragma unroll
        for (int j = 0; j < 4; j++) {
          float s = st[t][j];
          if (masked) {
            int kv = kb + t * 16 + g * 4 + j;
            s = (kv > qrow) ? -__builtin_inff() : s;
          }
          p[t][j] = s;
          tmax = fmaxf(tmax, s);
        }
      tmax = fmaxf(tmax, __shfl_xor(tmax, 16));
      tmax = fmaxf(tmax, __shfl_xor(tmax, 32));

      if (!__all(tmax <= mrun + 8.f)) {   // defer-max: rescale only on growth
        const float mnew = fmaxf(mrun, tmax);
        const float esc = __expf(mrun - mnew);
        float es[4];
#pragma unroll
        for (int j = 0; j < 4; j++) es[j] = __shfl(esc, (lane & 48) + g * 4 + j);
#pragma unroll
        for (int dt = 0; dt < 8; dt++)
#pragma unroll
          for (int j = 0; j < 4; j++) oacc[dt][j] *= es[j];
        lrun *= esc;
        mrun = mnew;
      }
      float psum = 0.f;
#pragma unroll
      for (int t = 0; t < 4; t++)
#pragma unroll
        for (int j = 0; j < 4; j++) {
          float e = __expf(p[t][j] - mrun);
          p[t][j] = e;
          psum += e;
        }
      psum += __shfl_xor(psum, 16);
      psum += __shfl_xor(psum, 32);
      lrun += psum;

      // ---- write P (bf16) to per-wave LDS, row-XOR-swizzled 128B rows ----
#pragma unroll
      for (int t = 0; t < 4; t++)
#pragma unroll
        for (int pp = 0; pp < 2; pp++) {
          int kvl = t * 16 + g * 4 + pp * 2;
          unsigned int val = (unsigned)f2bf(p[t][pp * 2]) | ((unsigned)f2bf(p[t][pp * 2 + 1]) << 16);
          int off = r16 * 128 + ((kvl * 2) ^ ((r16 & 7) << 4));
          *(unsigned int*)((char*)pw + off) = val;
        }

      // ---- PV: O += P * V  (O layout: q = g*4 + j, d = dt*16 + r16) ----
#pragma unroll
      for (int kc2 = 0; kc2 < 2; kc2++) {
        int c = kc2 * 4 + g;
        int cp = c ^ (r16 & 7);
        bf16x8 pa = *(const bf16x8*)(pw + r16 * 64 + cp * 8);
#pragma unroll
        for (int dt = 0; dt < 8; dt++) {
          int d = dt * 16 + r16;
          int cz = c ^ (d & 7);
          bf16x8 vf = *(const bf16x8*)(&Vs[cur][d * 64 + cz * 8]);
          oacc[dt] = __builtin_amdgcn_mfma_f32_16x16x32_bf16(pa, vf, oacc[dt], 0, 0, 0);
        }
      }
    }

    __syncthreads();  // all waves done with buf[cur]; prefetch drained
    cur ^= 1;
  }

  // ---- normalize + store ----
  float li[4];
#pragma unroll
  for (int j = 0; j < 4; j++)
    li[j] = 1.f / __shfl(lrun, (lane & 48) + g * 4 + j);
  u16* op = Og + ((long)(b * 2048 + qbase + w * 16 + g * 4)) * 4096 + h * 128 + r16;
#pragma unroll
  for (int dt = 0; dt < 8; dt++)
#pragma unroll
    for (int j = 0; j < 4; j++)
      op[(long)j * 4096 + dt * 16] = f2bf(oacc[dt][j] * li[j]);
}

// ---------------- launch ----------------
extern "C" void kernel_launch(void* const* d_in, const int* in_sizes, int n_in,
                              void* d_out, int out_size, void* d_ws, size_t ws_size,
                              hipStream_t stream) {
  (void)in_sizes; (void)n_in; (void)out_size; (void)ws_size;
  const float* x  = (const float*)d_in[0];
  const float* wq = (const float*)d_in[1];
  const float* wk = (const float*)d_in[2];
  const float* wv = (const float*)d_in[3];
  const float* wo = (const float*)d_in[4];
  float* out = (float*)d_out;

  u16* xb   = (u16*)d_ws;                       // 4096x4096 bf16 (x)
  u16* wqT  = xb  + (size_t)4096 * 4096;        // 4096x4096 (N,K), pre-scaled
  u16* wkT  = wqT + (size_t)4096 * 4096;        // 1024x4096
  u16* wvT  = wkT + (size_t)1024 * 4096;        // 1024x4096
  u16* woT  = wvT + (size_t)1024 * 4096;        // 4096x4096
  u16* qb   = woT + (size_t)4096 * 4096;        // 4096x4096 (B*S, NH*HD)
  u16* kbuf = qb  + (size_t)4096 * 4096;        // 4096x1024 (B*S, NKV*HD)
  u16* vT   = kbuf + (size_t)4096 * 1024;       // 1024x4096 (NKV*HD, B*S)
  u16* attn = vT  + (size_t)1024 * 4096;        // 4096x4096

  cast_f2b<<<2048, 256, 0, stream>>>(x, xb, 4096 * 4096 / 4);
  transpose_cast<<<dim3(128, 128), dim3(32, 8), 0, stream>>>(wq, wqT, 4096, 4096, SCALE_F);
  transpose_cast<<<dim3(32, 128),  dim3(32, 8), 0, stream>>>(wk, wkT, 4096, 1024, 1.0f);
  transpose_cast<<<dim3(32, 128),  dim3(32, 8), 0, stream>>>(wv, wvT, 4096, 1024, 1.0f);
  transpose_cast<<<dim3(128, 128), dim3(32, 8), 0, stream>>>(wo, woT, 4096, 4096, 1.0f);

  // q = x @ (wq*scale) ; k = x @ wk ; vT = (x @ wv)^T  (as wvT * xb^T)
  gemm_bt<1><<<dim3(32, 32), 256, 0, stream>>>(xb, wqT, qb, 4096, 4096, 4096);
  gemm_bt<1><<<dim3(8, 32),  256, 0, stream>>>(xb, wkT, kbuf, 4096, 1024, 4096);
  gemm_bt<1><<<dim3(32, 8),  256, 0, stream>>>(wvT, xb, vT, 1024, 4096, 4096);

  attn_fwd<<<dim3(16, 32, 2), 512, 0, stream>>>(qb, kbuf, vT, attn);

  gemm_bt<0><<<dim3(32, 32), 256, 0, stream>>>(attn, woT, out, 4096, 4096, 4096);
}

// Round 3
// 683.084 us; speedup vs baseline: 1.3441x; 1.2402x over previous
//
#include <hip/hip_runtime.h>
#include <cstdint>
#include <cstddef>

typedef __bf16 bf16x8 __attribute__((ext_vector_type(8)));
typedef float  f32x4  __attribute__((ext_vector_type(4)));
typedef unsigned short u16;

#define SCALE_F 0.08838834764831845f

__device__ __forceinline__ u16 f2bf(float f) {
  unsigned int u = __builtin_bit_cast(unsigned int, f);
  u += 0x7fffu + ((u >> 16) & 1u);
  return (u16)(u >> 16);
}

__device__ __forceinline__ void load_lds16(const void* g, void* l) {
  __builtin_amdgcn_global_load_lds((const __attribute__((address_space(1))) void*)g,
                                   (__attribute__((address_space(3))) void*)l,
                                   16, 0, 0);
}

// ---------------- elementwise f32 -> bf16 cast ----------------
__global__ __launch_bounds__(256) void cast_f2b(const float* __restrict__ in,
                                                u16* __restrict__ out, int n4) {
  int idx = blockIdx.x * 256 + threadIdx.x;
  const int stride = gridDim.x * 256;
  for (; idx < n4; idx += stride) {
    float4 v = ((const float4*)in)[idx];
    uint2 pk;
    pk.x = (unsigned)f2bf(v.x) | ((unsigned)f2bf(v.y) << 16);
    pk.y = (unsigned)f2bf(v.z) | ((unsigned)f2bf(v.w) << 16);
    ((uint2*)out)[idx] = pk;
  }
}

// ------- tiled transpose + cast + scale: in (R x C) f32 -> out (C x R) bf16 ----
__global__ void transpose_cast(const float* __restrict__ in, u16* __restrict__ out,
                               int R, int C, float scale) {
  __shared__ float tile[32][33];
  const int tx = threadIdx.x, ty = threadIdx.y;
  const long c0 = (long)blockIdx.x * 32, r0 = (long)blockIdx.y * 32;
#pragma unroll
  for (int i = 0; i < 4; i++)
    tile[ty + i * 8][tx] = in[(r0 + ty + i * 8) * (long)C + c0 + tx];
  __syncthreads();
#pragma unroll
  for (int i = 0; i < 4; i++)
    out[(c0 + ty + i * 8) * (long)R + r0 + tx] = f2bf(tile[tx][ty + i * 8] * scale);
}

// ---------------- m97-structure bf16 GEMM (kept for the skinny k/v projections)
template <int BF16_OUT>
__global__ __launch_bounds__(256) void gemm_bt(const u16* __restrict__ A,
                                               const u16* __restrict__ Bt,
                                               void* __restrict__ Cv,
                                               int M, int N, int K) {
  __shared__ u16 As[128 * 32];
  __shared__ u16 Bs[128 * 32];
  const int tid = threadIdx.x;
  const int lane = tid & 63;
  const int g = lane >> 4, r16 = lane & 15;
  const int wid = tid >> 6;
  const int wr = wid >> 1, wc = wid & 1;
  const long bm = (long)blockIdx.y * 128, bn = (long)blockIdx.x * 128;

  const u16* gA = A + (bm + (tid >> 2)) * (long)K + (tid & 3) * 8;
  const u16* gB = Bt + (bn + (tid >> 2)) * (long)K + (tid & 3) * 8;
  u16* lA = As + tid * 8;
  u16* lB = Bs + tid * 8;

  f32x4 acc[4][4];
#pragma unroll
  for (int m = 0; m < 4; m++)
#pragma unroll
    for (int n = 0; n < 4; n++)
#pragma unroll
      for (int j = 0; j < 4; j++) acc[m][n][j] = 0.f;

  for (int k0 = 0; k0 < K; k0 += 32) {
    load_lds16(gA + k0, lA);
    load_lds16(gA + 64 * (long)K + k0, lA + 256 * 8);
    load_lds16(gB + k0, lB);
    load_lds16(gB + 64 * (long)K + k0, lB + 256 * 8);
    __syncthreads();
    bf16x8 af[4], bfr[4];
#pragma unroll
    for (int m = 0; m < 4; m++)
      af[m] = *(const bf16x8*)(As + (wr * 64 + m * 16 + r16) * 32 + g * 8);
#pragma unroll
    for (int n = 0; n < 4; n++)
      bfr[n] = *(const bf16x8*)(Bs + (wc * 64 + n * 16 + r16) * 32 + g * 8);
#pragma unroll
    for (int m = 0; m < 4; m++)
#pragma unroll
      for (int n = 0; n < 4; n++)
        acc[m][n] = __builtin_amdgcn_mfma_f32_16x16x32_bf16(af[m], bfr[n], acc[m][n], 0, 0, 0);
    __syncthreads();
  }

  const long crow = bm + wr * 64 + g * 4;
  const long ccol = bn + wc * 64 + r16;
  if (BF16_OUT) {
    u16* C = (u16*)Cv;
#pragma unroll
    for (int m = 0; m < 4; m++)
#pragma unroll
      for (int n = 0; n < 4; n++)
#pragma unroll
        for (int j = 0; j < 4; j++)
          C[(crow + m * 16 + j) * (long)N + ccol + n * 16] = f2bf(acc[m][n][j]);
  } else {
    float* C = (float*)Cv;
#pragma unroll
    for (int m = 0; m < 4; m++)
#pragma unroll
      for (int n = 0; n < 4; n++)
#pragma unroll
        for (int j = 0; j < 4; j++)
          C[(crow + m * 16 + j) * (long)N + ccol + n * 16] = acc[m][n][j];
  }
}

// ---------------- 256x256 8-phase bf16 GEMM: C[M,N] = A[M,K] * Bt[N,K]^T ------
// 512 thr = 8 waves (2M x 4N); BK=64 as two 32-col k-slices; LDS 128 KiB =
// 2 dbuf x {A,B} x 2 kslice x [128 row-pairs][64 u16]. Counted vmcnt(8) on even
// phases only (2-stage in-flight allowance); stage->consume lead 5-6 phases.
// LDS tile packs 2 global rows per 128B LDS row; chunk-XOR swizzle applied via
// pre-swizzled GLOBAL source + linear global_load_lds dest (rule #21).
#define STGA(db, ks, KC) { int kc_ = (KC) < K ? (KC) : 0; \
    load_lds16(gA0 + kc_, &SA[db][ks][s0 * 8]); \
    load_lds16(gA1 + kc_, &SA[db][ks][s1 * 8]); }
#define STGB(db, ks, KC) { int kc_ = (KC) < K ? (KC) : 0; \
    load_lds16(gB0 + kc_, &SB[db][ks][s0 * 8]); \
    load_lds16(gB1 + kc_, &SB[db][ks][s1 * 8]); }

#define PHASE(DB, KS, MB, LOADB, STG, DOVM) { \
    bf16x8 afr[4]; \
    if (LOADB) { \
      _Pragma("unroll") for (int n = 0; n < 4; n++) \
        bfr[n] = *(const bf16x8*)(&SB[DB][KS][boff + n * 512]); \
    } \
    _Pragma("unroll") for (int mm = 0; mm < 4; mm++) \
      afr[mm] = *(const bf16x8*)(&SA[DB][KS][aoff + (MB + mm) * 512]); \
    STG; \
    if (DOVM) asm volatile("s_waitcnt vmcnt(8)" ::: "memory"); \
    __builtin_amdgcn_s_barrier(); \
    asm volatile("s_waitcnt lgkmcnt(0)" ::: "memory"); \
    __builtin_amdgcn_sched_barrier(0); \
    __builtin_amdgcn_s_setprio(1); \
    _Pragma("unroll") for (int mm = 0; mm < 4; mm++) \
      _Pragma("unroll") for (int n = 0; n < 4; n++) \
        acc[MB + mm][n] = __builtin_amdgcn_mfma_f32_16x16x32_bf16(afr[mm], bfr[n], acc[MB + mm][n], 0, 0, 0); \
    __builtin_amdgcn_s_setprio(0); \
    __builtin_amdgcn_sched_barrier(0); \
    asm volatile("" ::: "memory"); \
    __builtin_amdgcn_s_barrier(); \
    asm volatile("" ::: "memory"); \
  }

template <int BF16_OUT>
__global__ __launch_bounds__(512, 2) void gemm256(const u16* __restrict__ A,
                                                  const u16* __restrict__ Bt,
                                                  void* __restrict__ Cv,
                                                  int M, int N, int K, int NBX) {
  __shared__ u16 SA[2][2][8192];
  __shared__ u16 SB[2][2][8192];
  const int tid = threadIdx.x;
  const int lane = tid & 63;
  const int g = lane >> 4, r16 = lane & 15;
  const int wid = tid >> 6;
  const int wm = wid >> 2, wn = wid & 3;

  // XCD-chunked bijective remap (grid divisible by 8)
  const int cpx = gridDim.x >> 3;
  const int lin = (blockIdx.x & 7) * cpx + (blockIdx.x >> 3);
  const long bm = (long)(lin / NBX) * 256;
  const long bn = (long)(lin % NBX) * 256;

  // staging constants: slot s -> LDS (row-pair rp, chunk c); global src holds
  // chunk_in = c ^ (rp&7): row = rp*2 + (chunk_in>>2), colchunk = chunk_in&3.
  const int s0 = tid, s1 = 512 + tid;
  const int rp0 = s0 >> 3, ci0 = (s0 & 7) ^ (rp0 & 7);
  const int rp1 = s1 >> 3, ci1 = (s1 & 7) ^ (rp1 & 7);
  const long gr0 = rp0 * 2 + (ci0 >> 2), gc0 = (ci0 & 3) * 8;
  const long gr1 = rp1 * 2 + (ci1 >> 2), gc1 = (ci1 & 3) * 8;
  const u16* gA0 = A + (bm + gr0) * K + gc0;
  const u16* gA1 = A + (bm + gr1) * K + gc1;
  const u16* gB0 = Bt + (bn + gr0) * K + gc0;
  const u16* gB1 = Bt + (bn + gr1) * K + gc1;

  // fragment-read offsets (u16 units); chunk-XOR constant per thread since
  // frag rows step by 16 (rp steps by 8 -> (rp&7) invariant).
  const int rA = wm * 128 + r16;
  const int aoff = (rA >> 1) * 64 + ((((rA & 1) << 2) + g) ^ ((rA >> 1) & 7)) * 8;
  const int rB = wn * 64 + r16;
  const int boff = (rB >> 1) * 64 + ((((rB & 1) << 2) + g) ^ ((rB >> 1) & 7)) * 8;

  f32x4 acc[8][4];
#pragma unroll
  for (int m = 0; m < 8; m++)
#pragma unroll
    for (int n = 0; n < 4; n++)
#pragma unroll
      for (int j = 0; j < 4; j++) acc[m][n][j] = 0.f;
  bf16x8 bfr[4];

  // prologue: stage [t0,k0],[t0,k1],[t1,k0]; first pair confirmed landed
  STGA(0, 0, 0); STGB(0, 0, 0);
  STGA(0, 1, 32); STGB(0, 1, 32);
  STGA(1, 0, 64); STGB(1, 0, 64);
  asm volatile("s_waitcnt vmcnt(8)" ::: "memory");
  __builtin_amdgcn_s_barrier();
  asm volatile("" ::: "memory");

  for (int it = 0; it < K / 128; it++) {
    const int t0 = it * 128;
    PHASE(0, 0, 0, 1, STGA(1, 1, t0 + 96), 0);
    PHASE(0, 0, 4, 0, STGB(1, 1, t0 + 96), 1);
    PHASE(0, 1, 0, 1, STGA(0, 0, t0 + 128), 0);
    PHASE(0, 1, 4, 0, STGB(0, 0, t0 + 128), 1);
    PHASE(1, 0, 0, 1, STGA(0, 1, t0 + 160), 0);
    PHASE(1, 0, 4, 0, STGB(0, 1, t0 + 160), 1);
    PHASE(1, 1, 0, 1, STGA(1, 0, t0 + 192), 0);
    PHASE(1, 1, 4, 0, STGB(1, 0, t0 + 192), 1);
  }

  const long crow = bm + wm * 128 + g * 4;
  const long ccol = bn + wn * 64 + r16;
  if (BF16_OUT) {
    u16* C = (u16*)Cv;
#pragma unroll
    for (int m = 0; m < 8; m++)
#pragma unroll
      for (int n = 0; n < 4; n++)
#pragma unroll
        for (int j = 0; j < 4; j++)
          C[(crow + m * 16 + j) * (long)N + ccol + n * 16] = f2bf(acc[m][n][j]);
  } else {
    float* C = (float*)Cv;
#pragma unroll
    for (int m = 0; m < 8; m++)
#pragma unroll
      for (int n = 0; n < 4; n++)
#pragma unroll
        for (int j = 0; j < 4; j++)
          C[(crow + m * 16 + j) * (long)N + ccol + n * 16] = acc[m][n][j];
  }
}

// ---------------- causal GQA flash attention (v2, unchanged) ----------------
__global__ __launch_bounds__(512, 4) void attn_fwd(const u16* __restrict__ Q,
                                                   const u16* __restrict__ Kg,
                                                   const u16* __restrict__ VT,
                                                   u16* __restrict__ Og) {
  __shared__ u16 Ks[2][64 * 128];
  __shared__ u16 Vs[2][128 * 64];
  __shared__ u16 Ps[8][16 * 64];
  const int tid = threadIdx.x;
  const int lane = tid & 63;
  const int w = tid >> 6;
  const int g = lane >> 4, r16 = lane & 15;
  const int qt = blockIdx.x, h = blockIdx.y, b = blockIdx.z;
  const int kvh = h >> 2;        // NREP = 4
  const int qbase = qt * 128;
  const int qlo = qbase + w * 16;
  const int qrow = qlo + r16;

  bf16x8 qf[4];
  {
    const u16* qp = Q + ((long)(b * 2048 + qrow)) * 4096 + h * 128 + g * 8;
#pragma unroll
    for (int kc = 0; kc < 4; kc++) qf[kc] = *(const bf16x8*)(qp + kc * 32);
  }

  f32x4 oacc[8];
#pragma unroll
  for (int dt = 0; dt < 8; dt++)
#pragma unroll
    for (int j = 0; j < 4; j++) oacc[dt][j] = 0.f;
  float mrun = -__builtin_inff(), lrun = 0.f;

  const u16* kb_ptr = Kg + ((long)b * 2048) * 1024 + kvh * 128;
  const u16* vb_ptr = VT + ((long)kvh * 128) * 4096 + (long)b * 2048;
  u16* pw = Ps[w];

  const int nkt = 2 * (qt + 1);

  auto stage = [&](int bf, int kb) {
#pragma unroll
    for (int i = 0; i < 2; i++) {
      int slot = i * 512 + tid;
      int r = slot >> 4, cs = slot & 15;
      int ck = (cs & 8) | ((cs ^ r) & 7);
      load_lds16(kb_ptr + (long)(kb + r) * 1024 + ck * 8, &Ks[bf][slot * 8]);
      int d = slot >> 3, c8 = slot & 7;
      int cv = (c8 ^ d) & 7;
      load_lds16(vb_ptr + (long)d * 4096 + kb + cv * 8, &Vs[bf][slot * 8]);
    }
  };

  stage(0, 0);
  __syncthreads();
  int cur = 0;

  for (int kt = 0; kt < nkt; kt++) {
    const int kb = kt * 64;
    if (kt + 1 < nkt) stage(cur ^ 1, kb + 64);

    if (kb <= qlo + 15) {
      const bool masked = (kb + 63 > qlo);

      f32x4 st[4];
#pragma unroll
      for (int t = 0; t < 4; t++)
#pragma unroll
        for (int j = 0; j < 4; j++) st[t][j] = 0.f;
#pragma unroll
      for (int t = 0; t < 4; t++) {
        const int r = t * 16 + r16;
#pragma unroll
        for (int kc = 0; kc < 4; kc++) {
          int c = kc * 4 + g;
          int cz = (c & 8) | ((c ^ r) & 7);
          bf16x8 kf = *(const bf16x8*)(&Ks[cur][r * 128 + cz * 8]);
          st[t] = __builtin_amdgcn_mfma_f32_16x16x32_bf16(kf, qf[kc], st[t], 0, 0, 0);
        }
      }

      float p[4][4];
      float tmax = -__builtin_inff();
#pragma unroll
      for (int t = 0; t < 4; t++)
#pragma unroll
        for (int j = 0; j < 4; j++) {
          float s = st[t][j];
          if (masked) {
            int kv = kb + t * 16 + g * 4 + j;
            s = (kv > qrow) ? -__builtin_inff() : s;
          }
          p[t][j] = s;
          tmax = fmaxf(tmax, s);
        }
      tmax = fmaxf(tmax, __shfl_xor(tmax, 16));
      tmax = fmaxf(tmax, __shfl_xor(tmax, 32));

      if (!__all(tmax <= mrun + 8.f)) {
        const float mnew = fmaxf(mrun, tmax);
        const float esc = __expf(mrun - mnew);
        float es[4];
#pragma unroll
        for (int j = 0; j < 4; j++) es[j] = __shfl(esc, (lane & 48) + g * 4 + j);
#pragma unroll
        for (int dt = 0; dt < 8; dt++)
#pragma unroll
          for (int j = 0; j < 4; j++) oacc[dt][j] *= es[j];
        lrun *= esc;
        mrun = mnew;
      }
      float psum = 0.f;
#pragma unroll
      for (int t = 0; t < 4; t++)
#pragma unroll
        for (int j = 0; j < 4; j++) {
          float e = __expf(p[t][j] - mrun);
          p[t][j] = e;
          psum += e;
        }
      psum += __shfl_xor(psum, 16);
      psum += __shfl_xor(psum, 32);
      lrun += psum;

#pragma unroll
      for (int t = 0; t < 4; t++)
#pragma unroll
        for (int pp = 0; pp < 2; pp++) {
          int kvl = t * 16 + g * 4 + pp * 2;
          unsigned int val = (unsigned)f2bf(p[t][pp * 2]) | ((unsigned)f2bf(p[t][pp * 2 + 1]) << 16);
          int off = r16 * 128 + ((kvl * 2) ^ ((r16 & 7) << 4));
          *(unsigned int*)((char*)pw + off) = val;
        }

#pragma unroll
      for (int kc2 = 0; kc2 < 2; kc2++) {
        int c = kc2 * 4 + g;
        int cp = c ^ (r16 & 7);
        bf16x8 pa = *(const bf16x8*)(pw + r16 * 64 + cp * 8);
#pragma unroll
        for (int dt = 0; dt < 8; dt++) {
          int d = dt * 16 + r16;
          int cz = c ^ (d & 7);
          bf16x8 vf = *(const bf16x8*)(&Vs[cur][d * 64 + cz * 8]);
          oacc[dt] = __builtin_amdgcn_mfma_f32_16x16x32_bf16(pa, vf, oacc[dt], 0, 0, 0);
        }
      }
    }

    __syncthreads();
    cur ^= 1;
  }

  float li[4];
#pragma unroll
  for (int j = 0; j < 4; j++)
    li[j] = 1.f / __shfl(lrun, (lane & 48) + g * 4 + j);
  u16* op = Og + ((long)(b * 2048 + qbase + w * 16 + g * 4)) * 4096 + h * 128 + r16;
#pragma unroll
  for (int dt = 0; dt < 8; dt++)
#pragma unroll
    for (int j = 0; j < 4; j++)
      op[(long)j * 4096 + dt * 16] = f2bf(oacc[dt][j] * li[j]);
}

// ---------------- launch ----------------
extern "C" void kernel_launch(void* const* d_in, const int* in_sizes, int n_in,
                              void* d_out, int out_size, void* d_ws, size_t ws_size,
                              hipStream_t stream) {
  (void)in_sizes; (void)n_in; (void)out_size; (void)ws_size;
  const float* x  = (const float*)d_in[0];
  const float* wq = (const float*)d_in[1];
  const float* wk = (const float*)d_in[2];
  const float* wv = (const float*)d_in[3];
  const float* wo = (const float*)d_in[4];
  float* out = (float*)d_out;

  u16* xb   = (u16*)d_ws;                       // 4096x4096 bf16 (x)
  u16* wqT  = xb  + (size_t)4096 * 4096;        // 4096x4096 (N,K), pre-scaled
  u16* wkT  = wqT + (size_t)4096 * 4096;        // 1024x4096
  u16* wvT  = wkT + (size_t)1024 * 4096;        // 1024x4096
  u16* woT  = wvT + (size_t)1024 * 4096;        // 4096x4096
  u16* qb   = woT + (size_t)4096 * 4096;        // 4096x4096 (B*S, NH*HD)
  u16* kbuf = qb  + (size_t)4096 * 4096;        // 4096x1024 (B*S, NKV*HD)
  u16* vT   = kbuf + (size_t)4096 * 1024;       // 1024x4096 (NKV*HD, B*S)
  u16* attn = vT  + (size_t)1024 * 4096;        // 4096x4096

  cast_f2b<<<2048, 256, 0, stream>>>(x, xb, 4096 * 4096 / 4);
  transpose_cast<<<dim3(128, 128), dim3(32, 8), 0, stream>>>(wq, wqT, 4096, 4096, SCALE_F);
  transpose_cast<<<dim3(32, 128),  dim3(32, 8), 0, stream>>>(wk, wkT, 4096, 1024, 1.0f);
  transpose_cast<<<dim3(32, 128),  dim3(32, 8), 0, stream>>>(wv, wvT, 4096, 1024, 1.0f);
  transpose_cast<<<dim3(128, 128), dim3(32, 8), 0, stream>>>(wo, woT, 4096, 4096, 1.0f);

  // q = x @ (wq*scale) ; k = x @ wk ; vT = (x @ wv)^T  (as wvT * xb^T)
  gemm256<1><<<256, 512, 0, stream>>>(xb, wqT, qb, 4096, 4096, 4096, 16);
  gemm_bt<1><<<dim3(8, 32),  256, 0, stream>>>(xb, wkT, kbuf, 4096, 1024, 4096);
  gemm_bt<1><<<dim3(32, 8),  256, 0, stream>>>(wvT, xb, vT, 1024, 4096, 4096);

  attn_fwd<<<dim3(16, 32, 2), 512, 0, stream>>>(qb, kbuf, vT, attn);

  gemm256<0><<<256, 512, 0, stream>>>(attn, woT, out, 4096, 4096, 4096, 16);
}

// Round 4
// 620.504 us; speedup vs baseline: 1.4797x; 1.1009x over previous
//
#include <hip/hip_runtime.h>
#include <cstdint>
#include <cstddef>

typedef __bf16 bf16x8 __attribute__((ext_vector_type(8)));
typedef float  f32x4  __attribute__((ext_vector_type(4)));
typedef unsigned short u16;

#define SCALE_F 0.08838834764831845f
#define QSCALE_F (0.08838834764831845f * 1.4426950408889634f)  // SCALE * log2(e)

__device__ __forceinline__ u16 f2bf(float f) {
  unsigned int u = __builtin_bit_cast(unsigned int, f);
  u += 0x7fffu + ((u >> 16) & 1u);
  return (u16)(u >> 16);
}

__device__ __forceinline__ unsigned cvt_pk_bf16(float lo, float hi) {
  unsigned r;
  asm("v_cvt_pk_bf16_f32 %0, %1, %2" : "=v"(r) : "v"(lo), "v"(hi));
  return r;
}

__device__ __forceinline__ void load_lds16(const void* g, void* l) {
  __builtin_amdgcn_global_load_lds((const __attribute__((address_space(1))) void*)g,
                                   (__attribute__((address_space(3))) void*)l,
                                   16, 0, 0);
}

// ---------------- elementwise f32 -> bf16 cast ----------------
__global__ __launch_bounds__(256) void cast_f2b(const float* __restrict__ in,
                                                u16* __restrict__ out, int n4) {
  int idx = blockIdx.x * 256 + threadIdx.x;
  const int stride = gridDim.x * 256;
  for (; idx < n4; idx += stride) {
    float4 v = ((const float4*)in)[idx];
    uint2 pk;
    pk.x = (unsigned)f2bf(v.x) | ((unsigned)f2bf(v.y) << 16);
    pk.y = (unsigned)f2bf(v.z) | ((unsigned)f2bf(v.w) << 16);
    ((uint2*)out)[idx] = pk;
  }
}

// ------- tiled transpose + cast + scale: in (R x C) f32 -> out (C x R) bf16 ----
__global__ void transpose_cast(const float* __restrict__ in, u16* __restrict__ out,
                               int R, int C, float scale) {
  __shared__ float tile[32][33];
  const int tx = threadIdx.x, ty = threadIdx.y;
  const long c0 = (long)blockIdx.x * 32, r0 = (long)blockIdx.y * 32;
#pragma unroll
  for (int i = 0; i < 4; i++)
    tile[ty + i * 8][tx] = in[(r0 + ty + i * 8) * (long)C + c0 + tx];
  __syncthreads();
#pragma unroll
  for (int i = 0; i < 4; i++)
    out[(c0 + ty + i * 8) * (long)R + r0 + tx] = f2bf(tile[tx][ty + i * 8] * scale);
}

// ---------------- m97-structure bf16 GEMM (kept for the skinny v projection)
template <int BF16_OUT>
__global__ __launch_bounds__(256) void gemm_bt(const u16* __restrict__ A,
                                               const u16* __restrict__ Bt,
                                               void* __restrict__ Cv,
                                               int M, int N, int K) {
  __shared__ u16 As[128 * 32];
  __shared__ u16 Bs[128 * 32];
  const int tid = threadIdx.x;
  const int lane = tid & 63;
  const int g = lane >> 4, r16 = lane & 15;
  const int wid = tid >> 6;
  const int wr = wid >> 1, wc = wid & 1;
  const long bm = (long)blockIdx.y * 128, bn = (long)blockIdx.x * 128;

  const u16* gA = A + (bm + (tid >> 2)) * (long)K + (tid & 3) * 8;
  const u16* gB = Bt + (bn + (tid >> 2)) * (long)K + (tid & 3) * 8;
  u16* lA = As + tid * 8;
  u16* lB = Bs + tid * 8;

  f32x4 acc[4][4];
#pragma unroll
  for (int m = 0; m < 4; m++)
#pragma unroll
    for (int n = 0; n < 4; n++)
#pragma unroll
      for (int j = 0; j < 4; j++) acc[m][n][j] = 0.f;

  for (int k0 = 0; k0 < K; k0 += 32) {
    load_lds16(gA + k0, lA);
    load_lds16(gA + 64 * (long)K + k0, lA + 256 * 8);
    load_lds16(gB + k0, lB);
    load_lds16(gB + 64 * (long)K + k0, lB + 256 * 8);
    __syncthreads();
    bf16x8 af[4], bfr[4];
#pragma unroll
    for (int m = 0; m < 4; m++)
      af[m] = *(const bf16x8*)(As + (wr * 64 + m * 16 + r16) * 32 + g * 8);
#pragma unroll
    for (int n = 0; n < 4; n++)
      bfr[n] = *(const bf16x8*)(Bs + (wc * 64 + n * 16 + r16) * 32 + g * 8);
#pragma unroll
    for (int m = 0; m < 4; m++)
#pragma unroll
      for (int n = 0; n < 4; n++)
        acc[m][n] = __builtin_amdgcn_mfma_f32_16x16x32_bf16(af[m], bfr[n], acc[m][n], 0, 0, 0);
    __syncthreads();
  }

  const long crow = bm + wr * 64 + g * 4;
  const long ccol = bn + wc * 64 + r16;
  if (BF16_OUT) {
    u16* C = (u16*)Cv;
#pragma unroll
    for (int m = 0; m < 4; m++)
#pragma unroll
      for (int n = 0; n < 4; n++)
#pragma unroll
        for (int j = 0; j < 4; j++)
          C[(crow + m * 16 + j) * (long)N + ccol + n * 16] = f2bf(acc[m][n][j]);
  } else {
    float* C = (float*)Cv;
#pragma unroll
    for (int m = 0; m < 4; m++)
#pragma unroll
      for (int n = 0; n < 4; n++)
#pragma unroll
        for (int j = 0; j < 4; j++)
          C[(crow + m * 16 + j) * (long)N + ccol + n * 16] = acc[m][n][j];
  }
}

// ---------------- 256x256 8-phase bf16 GEMM: C[M,N] = A[M,K] * Bt[N,K]^T ------
#define STGA(db, ks, KC) { int kc_ = (KC) < K ? (KC) : 0; \
    load_lds16(gA0 + kc_, &SA[db][ks][s0 * 8]); \
    load_lds16(gA1 + kc_, &SA[db][ks][s1 * 8]); }
#define STGB(db, ks, KC) { int kc_ = (KC) < K ? (KC) : 0; \
    load_lds16(gB0 + kc_, &SB[db][ks][s0 * 8]); \
    load_lds16(gB1 + kc_, &SB[db][ks][s1 * 8]); }

#define PHASE(DB, KS, MB, LOADB, STG, DOVM) { \
    bf16x8 afr[4]; \
    if (LOADB) { \
      _Pragma("unroll") for (int n = 0; n < 4; n++) \
        bfr[n] = *(const bf16x8*)(&SB[DB][KS][boff + n * 512]); \
    } \
    _Pragma("unroll") for (int mm = 0; mm < 4; mm++) \
      afr[mm] = *(const bf16x8*)(&SA[DB][KS][aoff + (MB + mm) * 512]); \
    STG; \
    if (DOVM) asm volatile("s_waitcnt vmcnt(8)" ::: "memory"); \
    __builtin_amdgcn_s_barrier(); \
    asm volatile("s_waitcnt lgkmcnt(0)" ::: "memory"); \
    __builtin_amdgcn_sched_barrier(0); \
    __builtin_amdgcn_s_setprio(1); \
    _Pragma("unroll") for (int mm = 0; mm < 4; mm++) \
      _Pragma("unroll") for (int n = 0; n < 4; n++) \
        acc[MB + mm][n] = __builtin_amdgcn_mfma_f32_16x16x32_bf16(afr[mm], bfr[n], acc[MB + mm][n], 0, 0, 0); \
    __builtin_amdgcn_s_setprio(0); \
    __builtin_amdgcn_sched_barrier(0); \
    asm volatile("" ::: "memory"); \
    __builtin_amdgcn_s_barrier(); \
    asm volatile("" ::: "memory"); \
  }

template <int BF16_OUT>
__global__ __launch_bounds__(512, 2) void gemm256(const u16* __restrict__ A,
                                                  const u16* __restrict__ Bt,
                                                  void* __restrict__ Cv,
                                                  int M, int N, int K, int NBX) {
  __shared__ u16 SA[2][2][8192];
  __shared__ u16 SB[2][2][8192];
  const int tid = threadIdx.x;
  const int lane = tid & 63;
  const int g = lane >> 4, r16 = lane & 15;
  const int wid = tid >> 6;
  const int wm = wid >> 2, wn = wid & 3;

  const int cpx = gridDim.x >> 3;
  const int lin = (blockIdx.x & 7) * cpx + (blockIdx.x >> 3);
  const long bm = (long)(lin / NBX) * 256;
  const long bn = (long)(lin % NBX) * 256;

  const int s0 = tid, s1 = 512 + tid;
  const int rp0 = s0 >> 3, ci0 = (s0 & 7) ^ (rp0 & 7);
  const int rp1 = s1 >> 3, ci1 = (s1 & 7) ^ (rp1 & 7);
  const long gr0 = rp0 * 2 + (ci0 >> 2), gc0 = (ci0 & 3) * 8;
  const long gr1 = rp1 * 2 + (ci1 >> 2), gc1 = (ci1 & 3) * 8;
  const u16* gA0 = A + (bm + gr0) * K + gc0;
  const u16* gA1 = A + (bm + gr1) * K + gc1;
  const u16* gB0 = Bt + (bn + gr0) * K + gc0;
  const u16* gB1 = Bt + (bn + gr1) * K + gc1;

  const int rA = wm * 128 + r16;
  const int aoff = (rA >> 1) * 64 + ((((rA & 1) << 2) + g) ^ ((rA >> 1) & 7)) * 8;
  const int rB = wn * 64 + r16;
  const int boff = (rB >> 1) * 64 + ((((rB & 1) << 2) + g) ^ ((rB >> 1) & 7)) * 8;

  f32x4 acc[8][4];
#pragma unroll
  for (int m = 0; m < 8; m++)
#pragma unroll
    for (int n = 0; n < 4; n++)
#pragma unroll
      for (int j = 0; j < 4; j++) acc[m][n][j] = 0.f;
  bf16x8 bfr[4];

  STGA(0, 0, 0); STGB(0, 0, 0);
  STGA(0, 1, 32); STGB(0, 1, 32);
  STGA(1, 0, 64); STGB(1, 0, 64);
  asm volatile("s_waitcnt vmcnt(8)" ::: "memory");
  __builtin_amdgcn_s_barrier();
  asm volatile("" ::: "memory");

  for (int it = 0; it < K / 128; it++) {
    const int t0 = it * 128;
    PHASE(0, 0, 0, 1, STGA(1, 1, t0 + 96), 0);
    PHASE(0, 0, 4, 0, STGB(1, 1, t0 + 96), 1);
    PHASE(0, 1, 0, 1, STGA(0, 0, t0 + 128), 0);
    PHASE(0, 1, 4, 0, STGB(0, 0, t0 + 128), 1);
    PHASE(1, 0, 0, 1, STGA(0, 1, t0 + 160), 0);
    PHASE(1, 0, 4, 0, STGB(0, 1, t0 + 160), 1);
    PHASE(1, 1, 0, 1, STGA(1, 0, t0 + 192), 0);
    PHASE(1, 1, 4, 0, STGB(1, 0, t0 + 192), 1);
  }

  const long crow = bm + wm * 128 + g * 4;
  const long ccol = bn + wn * 64 + r16;
  if (BF16_OUT) {
    u16* C = (u16*)Cv;
#pragma unroll
    for (int m = 0; m < 8; m++)
#pragma unroll
      for (int n = 0; n < 4; n++)
#pragma unroll
        for (int j = 0; j < 4; j++)
          C[(crow + m * 16 + j) * (long)N + ccol + n * 16] = f2bf(acc[m][n][j]);
  } else {
    float* C = (float*)Cv;
#pragma unroll
    for (int m = 0; m < 8; m++)
#pragma unroll
      for (int n = 0; n < 4; n++)
#pragma unroll
        for (int j = 0; j < 4; j++)
          C[(crow + m * 16 + j) * (long)N + ccol + n * 16] = acc[m][n][j];
  }
}

// ---------------- causal GQA flash attention (v3) ----------------
// grid (8, NH, B); each block processes Q-tile pair (qt, 15-qt): 34 KV-tiles
// total for every block -> uniform duration, 512 blocks = exactly 2/CU.
// Q/K read from the fused QK buffer (row stride 5120; K at col offset 4096).
// exp2-domain softmax (Q pre-scaled by SCALE*log2e). cvt_pk P-pack.
__global__ __launch_bounds__(512, 4) void attn_fwd(const u16* __restrict__ QK,
                                                   const u16* __restrict__ VT,
                                                   u16* __restrict__ Og) {
  __shared__ u16 Ks[2][64 * 128];
  __shared__ u16 Vs[2][128 * 64];
  __shared__ u16 Ps[8][16 * 64];
  const int tid = threadIdx.x;
  const int lane = tid & 63;
  const int w = tid >> 6;
  const int g = lane >> 4, r16 = lane & 15;
  const int qtA = blockIdx.x;            // 0..7
  const int qtB = 15 - qtA;
  const int h = blockIdx.y, b = blockIdx.z;
  const int kvh = h >> 2;                // NREP = 4

  const u16* kcol  = QK + (long)b * 2048 * 5120 + 4096 + kvh * 128;
  const u16* vb_ptr = VT + (long)kvh * 128 * 4096 + (long)b * 2048;
  u16* pw = Ps[w];

  const int nktA = 2 * (qtA + 1);
  const int ntot = 34;                   // nktA + nktB

  int qbase = qtA * 128;
  int qlo = qbase + w * 16;
  int qrow = qlo + r16;

  bf16x8 qf[4];
  auto load_q = [&]() {
    const u16* qp = QK + ((long)(b * 2048 + qrow)) * 5120 + h * 128 + g * 8;
#pragma unroll
    for (int kc = 0; kc < 4; kc++) qf[kc] = *(const bf16x8*)(qp + kc * 32);
  };
  load_q();

  f32x4 oacc[8];
  float mrun, lrun;
  auto reinit = [&]() {
#pragma unroll
    for (int dt = 0; dt < 8; dt++)
#pragma unroll
      for (int j = 0; j < 4; j++) oacc[dt][j] = 0.f;
    mrun = -__builtin_inff();
    lrun = 0.f;
  };
  reinit();

  auto finalize = [&]() {
    float li[4];
#pragma unroll
    for (int j = 0; j < 4; j++)
      li[j] = 1.f / __shfl(lrun, (lane & 48) + g * 4 + j);
    u16* op = Og + ((long)(b * 2048 + qbase + w * 16 + g * 4)) * 4096 + h * 128 + r16;
#pragma unroll
    for (int dt = 0; dt < 8; dt++)
#pragma unroll
      for (int j = 0; j < 4; j++)
        op[(long)j * 4096 + dt * 16] = f2bf(oacc[dt][j] * li[j]);
  };

  // stage K (64x128) and V^T (128x64), chunk-XOR pre-swizzled global source +
  // linear global_load_lds dest (rule #21).
  auto stage = [&](int bf, int kb) {
#pragma unroll
    for (int i = 0; i < 2; i++) {
      int slot = i * 512 + tid;
      int r = slot >> 4, cs = slot & 15;
      int ck = (cs & 8) | ((cs ^ r) & 7);
      load_lds16(kcol + (long)(kb + r) * 5120 + ck * 8, &Ks[bf][slot * 8]);
      int d = slot >> 3, c8 = slot & 7;
      int cv = (c8 ^ d) & 7;
      load_lds16(vb_ptr + (long)d * 4096 + kb + cv * 8, &Vs[bf][slot * 8]);
    }
  };

  stage(0, 0);
  __syncthreads();
  int cur = 0;

  for (int i = 0; i < ntot; i++) {
    if (i == nktA) {  // block-uniform: finish Q-tile A, switch to B
      finalize();
      qbase = qtB * 128;
      qlo = qbase + w * 16;
      qrow = qlo + r16;
      load_q();
      reinit();
    }
    const int kt = (i < nktA) ? i : i - nktA;
    const int kb = kt * 64;
    if (i + 1 < ntot) {
      const int ktn = (i + 1 < nktA) ? i + 1 : i + 1 - nktA;
      stage(cur ^ 1, ktn * 64);          // prefetch overlaps compute
    }

    if (kb <= qlo + 15) {                // wave-uniform: skip masked tiles
      const bool masked = (kb + 63 > qlo);

      // ---- QK^T: S^T[kv][q] ----
      f32x4 st[4];
#pragma unroll
      for (int t = 0; t < 4; t++)
#pragma unroll
        for (int j = 0; j < 4; j++) st[t][j] = 0.f;
#pragma unroll
      for (int t = 0; t < 4; t++) {
        const int r = t * 16 + r16;
#pragma unroll
        for (int kc = 0; kc < 4; kc++) {
          int c = kc * 4 + g;
          int cz = (c & 8) | ((c ^ r) & 7);
          bf16x8 kf = *(const bf16x8*)(&Ks[cur][r * 128 + cz * 8]);
          st[t] = __builtin_amdgcn_mfma_f32_16x16x32_bf16(kf, qf[kc], st[t], 0, 0, 0);
        }
      }

      // ---- online softmax, log2 domain (kv = kb + t*16 + g*4 + j) ----
      float p[4][4];
      float tmax = -__builtin_inff();
#pragma unroll
      for (int t = 0; t < 4; t++)
#pragma unroll
        for (int j = 0; j < 4; j++) {
          float s = st[t][j];
          if (masked) {
            int kv = kb + t * 16 + g * 4 + j;
            s = (kv > qrow) ? -__builtin_inff() : s;
          }
          p[t][j] = s;
          tmax = fmaxf(tmax, s);
        }
      tmax = fmaxf(tmax, __shfl_xor(tmax, 16));
      tmax = fmaxf(tmax, __shfl_xor(tmax, 32));

      if (!__all(tmax <= mrun + 8.f)) {  // defer-max (2^8 headroom)
        const float mnew = fmaxf(mrun, tmax);
        const float esc = exp2f(mrun - mnew);
        float es[4];
#pragma unroll
        for (int j = 0; j < 4; j++) es[j] = __shfl(esc, (lane & 48) + g * 4 + j);
#pragma unroll
        for (int dt = 0; dt < 8; dt++)
#pragma unroll
          for (int j = 0; j < 4; j++) oacc[dt][j] *= es[j];
        lrun *= esc;
        mrun = mnew;
      }
      float psum = 0.f;
#pragma unroll
      for (int t = 0; t < 4; t++)
#pragma unroll
        for (int j = 0; j < 4; j++) {
          float e = exp2f(p[t][j] - mrun);
          p[t][j] = e;
          psum += e;
        }
      psum += __shfl_xor(psum, 16);
      psum += __shfl_xor(psum, 32);
      lrun += psum;

      // ---- write P (bf16 via cvt_pk) to per-wave LDS, row-XOR-swizzled ----
#pragma unroll
      for (int t = 0; t < 4; t++)
#pragma unroll
        for (int pp = 0; pp < 2; pp++) {
          int kvl = t * 16 + g * 4 + pp * 2;
          unsigned val = cvt_pk_bf16(p[t][pp * 2], p[t][pp * 2 + 1]);
          int off = r16 * 128 + ((kvl * 2) ^ ((r16 & 7) << 4));
          *(unsigned int*)((char*)pw + off) = val;
        }

      // ---- PV: O += P * V  (O layout: q = g*4 + j, d = dt*16 + r16) ----
#pragma unroll
      for (int kc2 = 0; kc2 < 2; kc2++) {
        int c = kc2 * 4 + g;
        int cp = c ^ (r16 & 7);
        bf16x8 pa = *(const bf16x8*)(pw + r16 * 64 + cp * 8);
#pragma unroll
        for (int dt = 0; dt < 8; dt++) {
          int d = dt * 16 + r16;
          int cz = c ^ (d & 7);
          bf16x8 vf = *(const bf16x8*)(&Vs[cur][d * 64 + cz * 8]);
          oacc[dt] = __builtin_amdgcn_mfma_f32_16x16x32_bf16(pa, vf, oacc[dt], 0, 0, 0);
        }
      }
    }

    __syncthreads();
    cur ^= 1;
  }

  finalize();
}

// ---------------- launch ----------------
extern "C" void kernel_launch(void* const* d_in, const int* in_sizes, int n_in,
                              void* d_out, int out_size, void* d_ws, size_t ws_size,
                              hipStream_t stream) {
  (void)in_sizes; (void)n_in; (void)out_size; (void)ws_size;
  const float* x  = (const float*)d_in[0];
  const float* wq = (const float*)d_in[1];
  const float* wk = (const float*)d_in[2];
  const float* wv = (const float*)d_in[3];
  const float* wo = (const float*)d_in[4];
  float* out = (float*)d_out;

  u16* xb    = (u16*)d_ws;                        // 4096x4096 bf16 (x)
  u16* wqkT  = xb   + (size_t)4096 * 4096;        // 5120x4096: wqT (scaled) | wkT
  u16* wvT   = wqkT + (size_t)5120 * 4096;        // 1024x4096
  u16* woT   = wvT  + (size_t)1024 * 4096;        // 4096x4096
  u16* qkb   = woT  + (size_t)4096 * 4096;        // 4096x5120 fused Q|K
  u16* vT    = qkb  + (size_t)4096 * 5120;        // 1024x4096 (NKV*HD, B*S)
  u16* attn  = vT   + (size_t)1024 * 4096;        // 4096x4096

  cast_f2b<<<2048, 256, 0, stream>>>(x, xb, 4096 * 4096 / 4);
  transpose_cast<<<dim3(128, 128), dim3(32, 8), 0, stream>>>(wq, wqkT, 4096, 4096, QSCALE_F);
  transpose_cast<<<dim3(32, 128),  dim3(32, 8), 0, stream>>>(wk, wqkT + (size_t)4096 * 4096, 4096, 1024, 1.0f);
  transpose_cast<<<dim3(32, 128),  dim3(32, 8), 0, stream>>>(wv, wvT, 4096, 1024, 1.0f);
  transpose_cast<<<dim3(128, 128), dim3(32, 8), 0, stream>>>(wo, woT, 4096, 4096, 1.0f);

  // [q|k] = x @ [wq*s | wk]  (fused, N=5120) ; vT = (x @ wv)^T via wvT * xb^T
  gemm256<1><<<320, 512, 0, stream>>>(xb, wqkT, qkb, 4096, 5120, 4096, 20);
  gemm_bt<1><<<dim3(32, 8), 256, 0, stream>>>(wvT, xb, vT, 1024, 4096, 4096);

  attn_fwd<<<dim3(8, 32, 2), 512, 0, stream>>>(qkb, vT, attn);

  gemm256<0><<<256, 512, 0, stream>>>(attn, woT, out, 4096, 4096, 4096, 16);
}

// Round 6
// 543.748 us; speedup vs baseline: 1.6886x; 1.1412x over previous
//
#include <hip/hip_runtime.h>
#include <cstdint>
#include <cstddef>

typedef __bf16 bf16x8 __attribute__((ext_vector_type(8)));
typedef float  f32x4  __attribute__((ext_vector_type(4)));
typedef unsigned short u16;

#define SCALE_F 0.08838834764831845f
#define QSCALE_F (0.08838834764831845f * 1.4426950408889634f)  // SCALE * log2(e)

__device__ __forceinline__ u16 f2bf(float f) {
  unsigned int u = __builtin_bit_cast(unsigned int, f);
  u += 0x7fffu + ((u >> 16) & 1u);
  return (u16)(u >> 16);
}

__device__ __forceinline__ unsigned cvt_pk_bf16(float lo, float hi) {
  unsigned r;
  asm("v_cvt_pk_bf16_f32 %0, %1, %2" : "=v"(r) : "v"(lo), "v"(hi));
  return r;
}

__device__ __forceinline__ void load_lds16(const void* g, void* l) {
  __builtin_amdgcn_global_load_lds((const __attribute__((address_space(1))) void*)g,
                                   (__attribute__((address_space(3))) void*)l,
                                   16, 0, 0);
}

// ---------------- elementwise f32 -> bf16 cast ----------------
__global__ __launch_bounds__(256) void cast_f2b(const float* __restrict__ in,
                                                u16* __restrict__ out, int n4) {
  int idx = blockIdx.x * 256 + threadIdx.x;
  const int stride = gridDim.x * 256;
  for (; idx < n4; idx += stride) {
    float4 v = ((const float4*)in)[idx];
    uint2 pk;
    pk.x = (unsigned)f2bf(v.x) | ((unsigned)f2bf(v.y) << 16);
    pk.y = (unsigned)f2bf(v.z) | ((unsigned)f2bf(v.w) << 16);
    ((uint2*)out)[idx] = pk;
  }
}

// ------- tiled transpose + cast + scale: in (R x C) f32 -> out (C x R) bf16 ----
__global__ void transpose_cast(const float* __restrict__ in, u16* __restrict__ out,
                               int R, int C, float scale) {
  __shared__ float tile[32][33];
  const int tx = threadIdx.x, ty = threadIdx.y;
  const long c0 = (long)blockIdx.x * 32, r0 = (long)blockIdx.y * 32;
#pragma unroll
  for (int i = 0; i < 4; i++)
    tile[ty + i * 8][tx] = in[(r0 + ty + i * 8) * (long)C + c0 + tx];
  __syncthreads();
#pragma unroll
  for (int i = 0; i < 4; i++)
    out[(c0 + ty + i * 8) * (long)R + r0 + tx] = f2bf(tile[tx][ty + i * 8] * scale);
}

// ------- strided u16 transpose: in R x C (ld=ldi) -> out C x R (ld=ldo) -------
__global__ __launch_bounds__(256) void transpose_u16(const u16* __restrict__ in,
                                                     u16* __restrict__ out,
                                                     int R, int C, int ldi, int ldo) {
  __shared__ u16 tile[32][33];
  const int tx = threadIdx.x, ty = threadIdx.y;
  const long c0 = (long)blockIdx.x * 32, r0 = (long)blockIdx.y * 32;
#pragma unroll
  for (int i = 0; i < 4; i++)
    tile[ty + i * 8][tx] = in[(r0 + ty + i * 8) * (long)ldi + c0 + tx];
  __syncthreads();
#pragma unroll
  for (int i = 0; i < 4; i++)
    out[(c0 + ty + i * 8) * (long)ldo + r0 + tx] = tile[tx][ty + i * 8];
}

// ---------------- 256x256 8-phase bf16 GEMM: C[M,N] = A[M,K] * Bt[N,K]^T ------
// 512 thr = 8 waves (2M x 4N); BK=64 as two 32-col k-slices; LDS 128 KiB.
// m201-faithful phase: {ds_read || STG -> [schedbar+vmcnt(8)] -> s_barrier ->
// lgkmcnt(0)+sched_barrier(0) (rule #18) -> setprio/MFMA -> s_barrier}.
// Prologue drains vmcnt(0) (reorder-proof); counted vmcnt elsewhere, never 0.
#define STGA(db, ks, KC) { int kc_ = (KC) < K ? (KC) : 0; \
    load_lds16(gA0 + kc_, &SA[db][ks][s0 * 8]); \
    load_lds16(gA1 + kc_, &SA[db][ks][s1 * 8]); }
#define STGB(db, ks, KC) { int kc_ = (KC) < K ? (KC) : 0; \
    load_lds16(gB0 + kc_, &SB[db][ks][s0 * 8]); \
    load_lds16(gB1 + kc_, &SB[db][ks][s1 * 8]); }

#define PHASE(DB, KS, MB, LOADB, STG, DOVM) { \
    bf16x8 afr[4]; \
    if (LOADB) { \
      _Pragma("unroll") for (int n = 0; n < 4; n++) \
        bfr[n] = *(const bf16x8*)(&SB[DB][KS][boff + n * 512]); \
    } \
    _Pragma("unroll") for (int mm = 0; mm < 4; mm++) \
      afr[mm] = *(const bf16x8*)(&SA[DB][KS][aoff + (MB + mm) * 512]); \
    STG; \
    if (DOVM) { \
      __builtin_amdgcn_sched_barrier(0); \
      asm volatile("s_waitcnt vmcnt(8)" ::: "memory"); \
    } \
    __builtin_amdgcn_s_barrier(); \
    asm volatile("s_waitcnt lgkmcnt(0)" ::: "memory"); \
    __builtin_amdgcn_sched_barrier(0); \
    __builtin_amdgcn_s_setprio(1); \
    _Pragma("unroll") for (int mm = 0; mm < 4; mm++) \
      _Pragma("unroll") for (int n = 0; n < 4; n++) \
        acc[MB + mm][n] = __builtin_amdgcn_mfma_f32_16x16x32_bf16(afr[mm], bfr[n], acc[MB + mm][n], 0, 0, 0); \
    __builtin_amdgcn_s_setprio(0); \
    __builtin_amdgcn_s_barrier(); \
  }

template <int BF16_OUT>
__global__ __launch_bounds__(512, 2) void gemm256(const u16* __restrict__ A,
                                                  const u16* __restrict__ Bt,
                                                  void* __restrict__ Cv,
                                                  int M, int N, int K, int NBX) {
  __shared__ u16 SA[2][2][8192];
  __shared__ u16 SB[2][2][8192];
  const int tid = threadIdx.x;
  const int lane = tid & 63;
  const int g = lane >> 4, r16 = lane & 15;
  const int wid = tid >> 6;
  const int wm = wid >> 2, wn = wid & 3;

  // XCD-chunked bijective remap (grid divisible by 8)
  const int cpx = gridDim.x >> 3;
  const int lin = (blockIdx.x & 7) * cpx + (blockIdx.x >> 3);
  const long bm = (long)(lin / NBX) * 256;
  const long bn = (long)(lin % NBX) * 256;

  // staging: slot s -> LDS (row-pair rp, chunk c); global src pre-swizzled
  const int s0 = tid, s1 = 512 + tid;
  const int rp0 = s0 >> 3, ci0 = (s0 & 7) ^ (rp0 & 7);
  const int rp1 = s1 >> 3, ci1 = (s1 & 7) ^ (rp1 & 7);
  const long gr0 = rp0 * 2 + (ci0 >> 2), gc0 = (ci0 & 3) * 8;
  const long gr1 = rp1 * 2 + (ci1 >> 2), gc1 = (ci1 & 3) * 8;
  const u16* gA0 = A + (bm + gr0) * K + gc0;
  const u16* gA1 = A + (bm + gr1) * K + gc1;
  const u16* gB0 = Bt + (bn + gr0) * K + gc0;
  const u16* gB1 = Bt + (bn + gr1) * K + gc1;

  const int rA = wm * 128 + r16;
  const int aoff = (rA >> 1) * 64 + ((((rA & 1) << 2) + g) ^ ((rA >> 1) & 7)) * 8;
  const int rB = wn * 64 + r16;
  const int boff = (rB >> 1) * 64 + ((((rB & 1) << 2) + g) ^ ((rB >> 1) & 7)) * 8;

  f32x4 acc[8][4];
#pragma unroll
  for (int m = 0; m < 8; m++)
#pragma unroll
    for (int n = 0; n < 4; n++)
#pragma unroll
      for (int j = 0; j < 4; j++) acc[m][n][j] = 0.f;
  bf16x8 bfr[4];

  // prologue: stage [t0,k0],[t0,k1],[t1,k0]; full drain (reorder-proof, 1x/block)
  STGA(0, 0, 0); STGB(0, 0, 0);
  STGA(0, 1, 32); STGB(0, 1, 32);
  STGA(1, 0, 64); STGB(1, 0, 64);
  __builtin_amdgcn_sched_barrier(0);
  asm volatile("s_waitcnt vmcnt(0)" ::: "memory");
  __builtin_amdgcn_s_barrier();

  for (int it = 0; it < K / 128; it++) {
    const int t0 = it * 128;
    PHASE(0, 0, 0, 1, STGA(1, 1, t0 + 96), 0);
    PHASE(0, 0, 4, 0, STGB(1, 1, t0 + 96), 1);
    PHASE(0, 1, 0, 1, STGA(0, 0, t0 + 128), 0);
    PHASE(0, 1, 4, 0, STGB(0, 0, t0 + 128), 1);
    PHASE(1, 0, 0, 1, STGA(0, 1, t0 + 160), 0);
    PHASE(1, 0, 4, 0, STGB(0, 1, t0 + 160), 1);
    PHASE(1, 1, 0, 1, STGA(1, 0, t0 + 192), 0);
    PHASE(1, 1, 4, 0, STGB(1, 0, t0 + 192), 1);
  }

  const long crow = bm + wm * 128 + g * 4;
  const long ccol = bn + wn * 64 + r16;
  if (BF16_OUT) {
    u16* C = (u16*)Cv;
#pragma unroll
    for (int m = 0; m < 8; m++)
#pragma unroll
      for (int n = 0; n < 4; n++)
#pragma unroll
        for (int j = 0; j < 4; j++)
          C[(crow + m * 16 + j) * (long)N + ccol + n * 16] = f2bf(acc[m][n][j]);
  } else {
    float* C = (float*)Cv;
#pragma unroll
    for (int m = 0; m < 8; m++)
#pragma unroll
      for (int n = 0; n < 4; n++)
#pragma unroll
        for (int j = 0; j < 4; j++)
          C[(crow + m * 16 + j) * (long)N + ccol + n * 16] = acc[m][n][j];
  }
}

// ---------------- causal GQA flash attention (v3; QKV stride 6144) ----------
// grid (8, NH, B); block processes Q-tile pair (qt, 15-qt): uniform 34 KV-tiles,
// 512 blocks = exactly 2/CU. exp2-domain softmax; defer-max; cvt_pk P-pack.
__global__ __launch_bounds__(512, 4) void attn_fwd(const u16* __restrict__ QK,
                                                   const u16* __restrict__ VT,
                                                   u16* __restrict__ Og) {
  __shared__ u16 Ks[2][64 * 128];
  __shared__ u16 Vs[2][128 * 64];
  __shared__ u16 Ps[8][16 * 64];
  const int tid = threadIdx.x;
  const int lane = tid & 63;
  const int w = tid >> 6;
  const int g = lane >> 4, r16 = lane & 15;
  const int qtA = blockIdx.x;            // 0..7
  const int qtB = 15 - qtA;
  const int h = blockIdx.y, b = blockIdx.z;
  const int kvh = h >> 2;                // NREP = 4

  const u16* kcol   = QK + (long)b * 2048 * 6144 + 4096 + kvh * 128;
  const u16* vb_ptr = VT + (long)kvh * 128 * 4096 + (long)b * 2048;
  u16* pw = Ps[w];

  const int nktA = 2 * (qtA + 1);
  const int ntot = 34;

  int qbase = qtA * 128;
  int qlo = qbase + w * 16;
  int qrow = qlo + r16;

  bf16x8 qf[4];
  auto load_q = [&]() {
    const u16* qp = QK + ((long)(b * 2048 + qrow)) * 6144 + h * 128 + g * 8;
#pragma unroll
    for (int kc = 0; kc < 4; kc++) qf[kc] = *(const bf16x8*)(qp + kc * 32);
  };
  load_q();

  f32x4 oacc[8];
  float mrun, lrun;
  auto reinit = [&]() {
#pragma unroll
    for (int dt = 0; dt < 8; dt++)
#pragma unroll
      for (int j = 0; j < 4; j++) oacc[dt][j] = 0.f;
    mrun = -__builtin_inff();
    lrun = 0.f;
  };
  reinit();

  auto finalize = [&]() {
    float li[4];
#pragma unroll
    for (int j = 0; j < 4; j++)
      li[j] = 1.f / __shfl(lrun, (lane & 48) + g * 4 + j);
    u16* op = Og + ((long)(b * 2048 + qbase + w * 16 + g * 4)) * 4096 + h * 128 + r16;
#pragma unroll
    for (int dt = 0; dt < 8; dt++)
#pragma unroll
      for (int j = 0; j < 4; j++)
        op[(long)j * 4096 + dt * 16] = f2bf(oacc[dt][j] * li[j]);
  };

  auto stage = [&](int bf, int kb) {
#pragma unroll
    for (int i = 0; i < 2; i++) {
      int slot = i * 512 + tid;
      int r = slot >> 4, cs = slot & 15;
      int ck = (cs & 8) | ((cs ^ r) & 7);
      load_lds16(kcol + (long)(kb + r) * 6144 + ck * 8, &Ks[bf][slot * 8]);
      int d = slot >> 3, c8 = slot & 7;
      int cv = (c8 ^ d) & 7;
      load_lds16(vb_ptr + (long)d * 4096 + kb + cv * 8, &Vs[bf][slot * 8]);
    }
  };

  stage(0, 0);
  __syncthreads();
  int cur = 0;

  for (int i = 0; i < ntot; i++) {
    if (i == nktA) {  // block-uniform: finish Q-tile A, switch to B
      finalize();
      qbase = qtB * 128;
      qlo = qbase + w * 16;
      qrow = qlo + r16;
      load_q();
      reinit();
    }
    const int kt = (i < nktA) ? i : i - nktA;
    const int kb = kt * 64;
    if (i + 1 < ntot) {
      const int ktn = (i + 1 < nktA) ? i + 1 : i + 1 - nktA;
      stage(cur ^ 1, ktn * 64);
    }

    if (kb <= qlo + 15) {
      const bool masked = (kb + 63 > qlo);

      f32x4 st[4];
#pragma unroll
      for (int t = 0; t < 4; t++)
#pragma unroll
        for (int j = 0; j < 4; j++) st[t][j] = 0.f;
#pragma unroll
      for (int t = 0; t < 4; t++) {
        const int r = t * 16 + r16;
#pragma unroll
        for (int kc = 0; kc < 4; kc++) {
          int c = kc * 4 + g;
          int cz = (c & 8) | ((c ^ r) & 7);
          bf16x8 kf = *(const bf16x8*)(&Ks[cur][r * 128 + cz * 8]);
          st[t] = __builtin_amdgcn_mfma_f32_16x16x32_bf16(kf, qf[kc], st[t], 0, 0, 0);
        }
      }

      float p[4][4];
      float tmax = -__builtin_inff();
#pragma unroll
      for (int t = 0; t < 4; t++)
#pragma unroll
        for (int j = 0; j < 4; j++) {
          float s = st[t][j];
          if (masked) {
            int kv = kb + t * 16 + g * 4 + j;
            s = (kv > qrow) ? -__builtin_inff() : s;
          }
          p[t][j] = s;
          tmax = fmaxf(tmax, s);
        }
      tmax = fmaxf(tmax, __shfl_xor(tmax, 16));
      tmax = fmaxf(tmax, __shfl_xor(tmax, 32));

      if (!__all(tmax <= mrun + 8.f)) {
        const float mnew = fmaxf(mrun, tmax);
        const float esc = exp2f(mrun - mnew);
        float es[4];
#pragma unroll
        for (int j = 0; j < 4; j++) es[j] = __shfl(esc, (lane & 48) + g * 4 + j);
#pragma unroll
        for (int dt = 0; dt < 8; dt++)
#pragma unroll
          for (int j = 0; j < 4; j++) oacc[dt][j] *= es[j];
        lrun *= esc;
        mrun = mnew;
      }
      float psum = 0.f;
#pragma unroll
      for (int t = 0; t < 4; t++)
#pragma unroll
        for (int j = 0; j < 4; j++) {
          float e = exp2f(p[t][j] - mrun);
          p[t][j] = e;
          psum += e;
        }
      psum += __shfl_xor(psum, 16);
      psum += __shfl_xor(psum, 32);
      lrun += psum;

#pragma unroll
      for (int t = 0; t < 4; t++)
#pragma unroll
        for (int pp = 0; pp < 2; pp++) {
          int kvl = t * 16 + g * 4 + pp * 2;
          unsigned val = cvt_pk_bf16(p[t][pp * 2], p[t][pp * 2 + 1]);
          int off = r16 * 128 + ((kvl * 2) ^ ((r16 & 7) << 4));
          *(unsigned int*)((char*)pw + off) = val;
        }

#pragma unroll
      for (int kc2 = 0; kc2 < 2; kc2++) {
        int c = kc2 * 4 + g;
        int cp = c ^ (r16 & 7);
        bf16x8 pa = *(const bf16x8*)(pw + r16 * 64 + cp * 8);
#pragma unroll
        for (int dt = 0; dt < 8; dt++) {
          int d = dt * 16 + r16;
          int cz = c ^ (d & 7);
          bf16x8 vf = *(const bf16x8*)(&Vs[cur][d * 64 + cz * 8]);
          oacc[dt] = __builtin_amdgcn_mfma_f32_16x16x32_bf16(pa, vf, oacc[dt], 0, 0, 0);
        }
      }
    }

    __syncthreads();
    cur ^= 1;
  }

  finalize();
}

// ---------------- launch ----------------
extern "C" void kernel_launch(void* const* d_in, const int* in_sizes, int n_in,
                              void* d_out, int out_size, void* d_ws, size_t ws_size,
                              hipStream_t stream) {
  (void)in_sizes; (void)n_in; (void)out_size; (void)ws_size;
  const float* x  = (const float*)d_in[0];
  const float* wq = (const float*)d_in[1];
  const float* wk = (const float*)d_in[2];
  const float* wv = (const float*)d_in[3];
  const float* wo = (const float*)d_in[4];
  float* out = (float*)d_out;

  u16* xb     = (u16*)d_ws;                         // 4096x4096 bf16 (x); reused as attn out
  u16* wqkvT  = xb    + (size_t)4096 * 4096;        // 6144x4096: wqT(scaled)|wkT|wvT
  u16* woT    = wqkvT + (size_t)6144 * 4096;        // 4096x4096
  u16* qkv    = woT   + (size_t)4096 * 4096;        // 4096x6144 fused Q|K|V
  u16* vT     = qkv   + (size_t)4096 * 6144;        // 1024x4096 (NKV*HD, B*S)
  u16* attn   = xb;                                 // xb dead after QKV gemm

  cast_f2b<<<2048, 256, 0, stream>>>(x, xb, 4096 * 4096 / 4);
  transpose_cast<<<dim3(128, 128), dim3(32, 8), 0, stream>>>(wq, wqkvT, 4096, 4096, QSCALE_F);
  transpose_cast<<<dim3(32, 128),  dim3(32, 8), 0, stream>>>(wk, wqkvT + (size_t)4096 * 4096, 4096, 1024, 1.0f);
  transpose_cast<<<dim3(32, 128),  dim3(32, 8), 0, stream>>>(wv, wqkvT + (size_t)5120 * 4096, 4096, 1024, 1.0f);
  transpose_cast<<<dim3(128, 128), dim3(32, 8), 0, stream>>>(wo, woT, 4096, 4096, 1.0f);

  // [q|k|v] = x @ [wq*s | wk | wv]  (fused, N=6144, grid 384 = 1.5 CU-waves)
  gemm256<1><<<384, 512, 0, stream>>>(xb, wqkvT, qkv, 4096, 6144, 4096, 24);
  // vT = transpose of the V panel (rows stride 6144)
  transpose_u16<<<dim3(32, 128), dim3(32, 8), 0, stream>>>(qkv + 5120, vT, 4096, 1024, 6144, 4096);

  attn_fwd<<<dim3(8, 32, 2), 512, 0, stream>>>(qkv, vT, attn);

  gemm256<0><<<256, 512, 0, stream>>>(attn, woT, out, 4096, 4096, 4096, 16);
}

// Round 7
// 537.433 us; speedup vs baseline: 1.7084x; 1.0117x over previous
//
#include <hip/hip_runtime.h>
#include <cstdint>
#include <cstddef>

typedef __bf16 bf16x8 __attribute__((ext_vector_type(8)));
typedef float  f32x4  __attribute__((ext_vector_type(4)));
typedef unsigned short u16;

#define SCALE_F 0.08838834764831845f
#define QSCALE_F (0.08838834764831845f * 1.4426950408889634f)  // SCALE * log2(e)

__device__ __forceinline__ u16 f2bf(float f) {
  unsigned int u = __builtin_bit_cast(unsigned int, f);
  u += 0x7fffu + ((u >> 16) & 1u);
  return (u16)(u >> 16);
}

__device__ __forceinline__ unsigned cvt_pk_bf16(float lo, float hi) {
  unsigned r;
  asm("v_cvt_pk_bf16_f32 %0, %1, %2" : "=v"(r) : "v"(lo), "v"(hi));
  return r;
}

__device__ __forceinline__ void load_lds16(const void* g, void* l) {
  __builtin_amdgcn_global_load_lds((const __attribute__((address_space(1))) void*)g,
                                   (__attribute__((address_space(3))) void*)l,
                                   16, 0, 0);
}

// ---------------- elementwise f32 -> bf16 cast ----------------
__global__ __launch_bounds__(256) void cast_f2b(const float* __restrict__ in,
                                                u16* __restrict__ out, int n4) {
  int idx = blockIdx.x * 256 + threadIdx.x;
  const int stride = gridDim.x * 256;
  for (; idx < n4; idx += stride) {
    float4 v = ((const float4*)in)[idx];
    uint2 pk;
    pk.x = (unsigned)f2bf(v.x) | ((unsigned)f2bf(v.y) << 16);
    pk.y = (unsigned)f2bf(v.z) | ((unsigned)f2bf(v.w) << 16);
    ((uint2*)out)[idx] = pk;
  }
}

// ------- tiled transpose + cast + scale: in (R x C) f32 -> out (C x R) bf16 ----
__global__ void transpose_cast(const float* __restrict__ in, u16* __restrict__ out,
                               int R, int C, float scale) {
  __shared__ float tile[32][33];
  const int tx = threadIdx.x, ty = threadIdx.y;
  const long c0 = (long)blockIdx.x * 32, r0 = (long)blockIdx.y * 32;
#pragma unroll
  for (int i = 0; i < 4; i++)
    tile[ty + i * 8][tx] = in[(r0 + ty + i * 8) * (long)C + c0 + tx];
  __syncthreads();
#pragma unroll
  for (int i = 0; i < 4; i++)
    out[(c0 + ty + i * 8) * (long)R + r0 + tx] = f2bf(tile[tx][ty + i * 8] * scale);
}

// ------- strided u16 transpose: in R x C (ld=ldi) -> out C x R (ld=ldo) -------
__global__ __launch_bounds__(256) void transpose_u16(const u16* __restrict__ in,
                                                     u16* __restrict__ out,
                                                     int R, int C, int ldi, int ldo) {
  __shared__ u16 tile[32][33];
  const int tx = threadIdx.x, ty = threadIdx.y;
  const long c0 = (long)blockIdx.x * 32, r0 = (long)blockIdx.y * 32;
#pragma unroll
  for (int i = 0; i < 4; i++)
    tile[ty + i * 8][tx] = in[(r0 + ty + i * 8) * (long)ldi + c0 + tx];
  __syncthreads();
#pragma unroll
  for (int i = 0; i < 4; i++)
    out[(c0 + ty + i * 8) * (long)ldo + r0 + tx] = tile[tx][ty + i * 8];
}

// ---------------- 256x256 8-phase bf16 GEMM: C[M,N] = A[M,K] * Bt[N,K]^T ------
// 512 thr = 8 waves (2M x 4N); BK=64 as two 32-col k-slices; LDS 128 KiB.
// SINGLE mid-phase barrier (v7): slot staged at phase p was last read at p-2
// (reads drained by lgkmcnt(0)@p-2, globalized by barrier p-2 < barrier p-1 <
// STG_p) and slice consumed at c is vmcnt-confirmed at c-1 + barrier. One-phase
// wave skew lets one wave's ds_reads overlap another's MFMA.
#define STGA(db, ks, KC) { int kc_ = (KC) < K ? (KC) : 0; \
    load_lds16(gA0 + kc_, &SA[db][ks][s0 * 8]); \
    load_lds16(gA1 + kc_, &SA[db][ks][s1 * 8]); }
#define STGB(db, ks, KC) { int kc_ = (KC) < K ? (KC) : 0; \
    load_lds16(gB0 + kc_, &SB[db][ks][s0 * 8]); \
    load_lds16(gB1 + kc_, &SB[db][ks][s1 * 8]); }

#define PHASE(DB, KS, MB, LOADB, STG, DOVM) { \
    bf16x8 afr[4]; \
    if (LOADB) { \
      _Pragma("unroll") for (int n = 0; n < 4; n++) \
        bfr[n] = *(const bf16x8*)(&SB[DB][KS][boff + n * 512]); \
    } \
    _Pragma("unroll") for (int mm = 0; mm < 4; mm++) \
      afr[mm] = *(const bf16x8*)(&SA[DB][KS][aoff + (MB + mm) * 512]); \
    STG; \
    if (DOVM) { \
      __builtin_amdgcn_sched_barrier(0); \
      asm volatile("s_waitcnt vmcnt(8)" ::: "memory"); \
    } \
    __builtin_amdgcn_s_barrier(); \
    asm volatile("s_waitcnt lgkmcnt(0)" ::: "memory"); \
    __builtin_amdgcn_sched_barrier(0); \
    __builtin_amdgcn_s_setprio(1); \
    _Pragma("unroll") for (int mm = 0; mm < 4; mm++) \
      _Pragma("unroll") for (int n = 0; n < 4; n++) \
        acc[MB + mm][n] = __builtin_amdgcn_mfma_f32_16x16x32_bf16(afr[mm], bfr[n], acc[MB + mm][n], 0, 0, 0); \
    __builtin_amdgcn_s_setprio(0); \
  }

template <int BF16_OUT>
__global__ __launch_bounds__(512, 2) void gemm256(const u16* __restrict__ A,
                                                  const u16* __restrict__ Bt,
                                                  void* __restrict__ Cv,
                                                  int M, int N, int K, int NBX) {
  __shared__ u16 SA[2][2][8192];
  __shared__ u16 SB[2][2][8192];
  const int tid = threadIdx.x;
  const int lane = tid & 63;
  const int g = lane >> 4, r16 = lane & 15;
  const int wid = tid >> 6;
  const int wm = wid >> 2, wn = wid & 3;

  // XCD-chunked bijective remap (grid divisible by 8)
  const int cpx = gridDim.x >> 3;
  const int lin = (blockIdx.x & 7) * cpx + (blockIdx.x >> 3);
  const long bm = (long)(lin / NBX) * 256;
  const long bn = (long)(lin % NBX) * 256;

  // staging: slot s -> LDS (row-pair rp, chunk c); global src pre-swizzled
  const int s0 = tid, s1 = 512 + tid;
  const int rp0 = s0 >> 3, ci0 = (s0 & 7) ^ (rp0 & 7);
  const int rp1 = s1 >> 3, ci1 = (s1 & 7) ^ (rp1 & 7);
  const long gr0 = rp0 * 2 + (ci0 >> 2), gc0 = (ci0 & 3) * 8;
  const long gr1 = rp1 * 2 + (ci1 >> 2), gc1 = (ci1 & 3) * 8;
  const u16* gA0 = A + (bm + gr0) * K + gc0;
  const u16* gA1 = A + (bm + gr1) * K + gc1;
  const u16* gB0 = Bt + (bn + gr0) * K + gc0;
  const u16* gB1 = Bt + (bn + gr1) * K + gc1;

  const int rA = wm * 128 + r16;
  const int aoff = (rA >> 1) * 64 + ((((rA & 1) << 2) + g) ^ ((rA >> 1) & 7)) * 8;
  const int rB = wn * 64 + r16;
  const int boff = (rB >> 1) * 64 + ((((rB & 1) << 2) + g) ^ ((rB >> 1) & 7)) * 8;

  f32x4 acc[8][4];
#pragma unroll
  for (int m = 0; m < 8; m++)
#pragma unroll
    for (int n = 0; n < 4; n++)
#pragma unroll
      for (int j = 0; j < 4; j++) acc[m][n][j] = 0.f;
  bf16x8 bfr[4];

  // prologue: stage [t0,k0],[t0,k1],[t1,k0]; full drain (reorder-proof, 1x/block)
  STGA(0, 0, 0); STGB(0, 0, 0);
  STGA(0, 1, 32); STGB(0, 1, 32);
  STGA(1, 0, 64); STGB(1, 0, 64);
  __builtin_amdgcn_sched_barrier(0);
  asm volatile("s_waitcnt vmcnt(0)" ::: "memory");
  __builtin_amdgcn_s_barrier();

  for (int it = 0; it < K / 128; it++) {
    const int t0 = it * 128;
    PHASE(0, 0, 0, 1, STGA(1, 1, t0 + 96), 0);
    PHASE(0, 0, 4, 0, STGB(1, 1, t0 + 96), 1);
    PHASE(0, 1, 0, 1, STGA(0, 0, t0 + 128), 0);
    PHASE(0, 1, 4, 0, STGB(0, 0, t0 + 128), 1);
    PHASE(1, 0, 0, 1, STGA(0, 1, t0 + 160), 0);
    PHASE(1, 0, 4, 0, STGB(0, 1, t0 + 160), 1);
    PHASE(1, 1, 0, 1, STGA(1, 0, t0 + 192), 0);
    PHASE(1, 1, 4, 0, STGB(1, 0, t0 + 192), 1);
  }

  const long crow = bm + wm * 128 + g * 4;
  const long ccol = bn + wn * 64 + r16;
  if (BF16_OUT) {
    u16* C = (u16*)Cv;
#pragma unroll
    for (int m = 0; m < 8; m++)
#pragma unroll
      for (int n = 0; n < 4; n++)
#pragma unroll
        for (int j = 0; j < 4; j++)
          C[(crow + m * 16 + j) * (long)N + ccol + n * 16] = f2bf(acc[m][n][j]);
  } else {
    float* C = (float*)Cv;
#pragma unroll
    for (int m = 0; m < 8; m++)
#pragma unroll
      for (int n = 0; n < 4; n++)
#pragma unroll
        for (int j = 0; j < 4; j++)
          C[(crow + m * 16 + j) * (long)N + ccol + n * 16] = acc[m][n][j];
  }
}

// ---------------- causal GQA flash attention (v3; QKV stride 6144) ----------
// grid (8, NH, B); block processes Q-tile pair (qt, 15-qt): uniform 34 KV-tiles,
// 512 blocks = exactly 2/CU. exp2-domain softmax; defer-max; cvt_pk P-pack.
__global__ __launch_bounds__(512, 4) void attn_fwd(const u16* __restrict__ QK,
                                                   const u16* __restrict__ VT,
                                                   u16* __restrict__ Og) {
  __shared__ u16 Ks[2][64 * 128];
  __shared__ u16 Vs[2][128 * 64];
  __shared__ u16 Ps[8][16 * 64];
  const int tid = threadIdx.x;
  const int lane = tid & 63;
  const int w = tid >> 6;
  const int g = lane >> 4, r16 = lane & 15;
  const int qtA = blockIdx.x;            // 0..7
  const int qtB = 15 - qtA;
  const int h = blockIdx.y, b = blockIdx.z;
  const int kvh = h >> 2;                // NREP = 4

  const u16* kcol   = QK + (long)b * 2048 * 6144 + 4096 + kvh * 128;
  const u16* vb_ptr = VT + (long)kvh * 128 * 4096 + (long)b * 2048;
  u16* pw = Ps[w];

  const int nktA = 2 * (qtA + 1);
  const int ntot = 34;

  int qbase = qtA * 128;
  int qlo = qbase + w * 16;
  int qrow = qlo + r16;

  bf16x8 qf[4];
  auto load_q = [&]() {
    const u16* qp = QK + ((long)(b * 2048 + qrow)) * 6144 + h * 128 + g * 8;
#pragma unroll
    for (int kc = 0; kc < 4; kc++) qf[kc] = *(const bf16x8*)(qp + kc * 32);
  };
  load_q();

  f32x4 oacc[8];
  float mrun, lrun;
  auto reinit = [&]() {
#pragma unroll
    for (int dt = 0; dt < 8; dt++)
#pragma unroll
      for (int j = 0; j < 4; j++) oacc[dt][j] = 0.f;
    mrun = -__builtin_inff();
    lrun = 0.f;
  };
  reinit();

  auto finalize = [&]() {
    float li[4];
#pragma unroll
    for (int j = 0; j < 4; j++)
      li[j] = 1.f / __shfl(lrun, (lane & 48) + g * 4 + j);
    u16* op = Og + ((long)(b * 2048 + qbase + w * 16 + g * 4)) * 4096 + h * 128 + r16;
#pragma unroll
    for (int dt = 0; dt < 8; dt++)
#pragma unroll
      for (int j = 0; j < 4; j++)
        op[(long)j * 4096 + dt * 16] = f2bf(oacc[dt][j] * li[j]);
  };

  auto stage = [&](int bf, int kb) {
#pragma unroll
    for (int i = 0; i < 2; i++) {
      int slot = i * 512 + tid;
      int r = slot >> 4, cs = slot & 15;
      int ck = (cs & 8) | ((cs ^ r) & 7);
      load_lds16(kcol + (long)(kb + r) * 6144 + ck * 8, &Ks[bf][slot * 8]);
      int d = slot >> 3, c8 = slot & 7;
      int cv = (c8 ^ d) & 7;
      load_lds16(vb_ptr + (long)d * 4096 + kb + cv * 8, &Vs[bf][slot * 8]);
    }
  };

  stage(0, 0);
  __syncthreads();
  int cur = 0;

  for (int i = 0; i < ntot; i++) {
    if (i == nktA) {  // block-uniform: finish Q-tile A, switch to B
      finalize();
      qbase = qtB * 128;
      qlo = qbase + w * 16;
      qrow = qlo + r16;
      load_q();
      reinit();
    }
    const int kt = (i < nktA) ? i : i - nktA;
    const int kb = kt * 64;
    if (i + 1 < ntot) {
      const int ktn = (i + 1 < nktA) ? i + 1 : i + 1 - nktA;
      stage(cur ^ 1, ktn * 64);
    }

    if (kb <= qlo + 15) {
      const bool masked = (kb + 63 > qlo);

      f32x4 st[4];
#pragma unroll
      for (int t = 0; t < 4; t++)
#pragma unroll
        for (int j = 0; j < 4; j++) st[t][j] = 0.f;
#pragma unroll
      for (int t = 0; t < 4; t++) {
        const int r = t * 16 + r16;
#pragma unroll
        for (int kc = 0; kc < 4; kc++) {
          int c = kc * 4 + g;
          int cz = (c & 8) | ((c ^ r) & 7);
          bf16x8 kf = *(const bf16x8*)(&Ks[cur][r * 128 + cz * 8]);
          st[t] = __builtin_amdgcn_mfma_f32_16x16x32_bf16(kf, qf[kc], st[t], 0, 0, 0);
        }
      }

      float p[4][4];
      float tmax = -__builtin_inff();
#pragma unroll
      for (int t = 0; t < 4; t++)
#pragma unroll
        for (int j = 0; j < 4; j++) {
          float s = st[t][j];
          if (masked) {
            int kv = kb + t * 16 + g * 4 + j;
            s = (kv > qrow) ? -__builtin_inff() : s;
          }
          p[t][j] = s;
          tmax = fmaxf(tmax, s);
        }
      tmax = fmaxf(tmax, __shfl_xor(tmax, 16));
      tmax = fmaxf(tmax, __shfl_xor(tmax, 32));

      if (!__all(tmax <= mrun + 8.f)) {
        const float mnew = fmaxf(mrun, tmax);
        const float esc = exp2f(mrun - mnew);
        float es[4];
#pragma unroll
        for (int j = 0; j < 4; j++) es[j] = __shfl(esc, (lane & 48) + g * 4 + j);
#pragma unroll
        for (int dt = 0; dt < 8; dt++)
#pragma unroll
          for (int j = 0; j < 4; j++) oacc[dt][j] *= es[j];
        lrun *= esc;
        mrun = mnew;
      }
      float psum = 0.f;
#pragma unroll
      for (int t = 0; t < 4; t++)
#pragma unroll
        for (int j = 0; j < 4; j++) {
          float e = exp2f(p[t][j] - mrun);
          p[t][j] = e;
          psum += e;
        }
      psum += __shfl_xor(psum, 16);
      psum += __shfl_xor(psum, 32);
      lrun += psum;

#pragma unroll
      for (int t = 0; t < 4; t++)
#pragma unroll
        for (int pp = 0; pp < 2; pp++) {
          int kvl = t * 16 + g * 4 + pp * 2;
          unsigned val = cvt_pk_bf16(p[t][pp * 2], p[t][pp * 2 + 1]);
          int off = r16 * 128 + ((kvl * 2) ^ ((r16 & 7) << 4));
          *(unsigned int*)((char*)pw + off) = val;
        }

#pragma unroll
      for (int kc2 = 0; kc2 < 2; kc2++) {
        int c = kc2 * 4 + g;
        int cp = c ^ (r16 & 7);
        bf16x8 pa = *(const bf16x8*)(pw + r16 * 64 + cp * 8);
#pragma unroll
        for (int dt = 0; dt < 8; dt++) {
          int d = dt * 16 + r16;
          int cz = c ^ (d & 7);
          bf16x8 vf = *(const bf16x8*)(&Vs[cur][d * 64 + cz * 8]);
          oacc[dt] = __builtin_amdgcn_mfma_f32_16x16x32_bf16(pa, vf, oacc[dt], 0, 0, 0);
        }
      }
    }

    __syncthreads();
    cur ^= 1;
  }

  finalize();
}

// ---------------- launch ----------------
extern "C" void kernel_launch(void* const* d_in, const int* in_sizes, int n_in,
                              void* d_out, int out_size, void* d_ws, size_t ws_size,
                              hipStream_t stream) {
  (void)in_sizes; (void)n_in; (void)out_size; (void)ws_size;
  const float* x  = (const float*)d_in[0];
  const float* wq = (const float*)d_in[1];
  const float* wk = (const float*)d_in[2];
  const float* wv = (const float*)d_in[3];
  const float* wo = (const float*)d_in[4];
  float* out = (float*)d_out;

  u16* xb     = (u16*)d_ws;                         // 4096x4096 bf16 (x); reused as attn out
  u16* wqkvT  = xb    + (size_t)4096 * 4096;        // 6144x4096: wqT(scaled)|wkT|wvT
  u16* woT    = wqkvT + (size_t)6144 * 4096;        // 4096x4096
  u16* qkv    = woT   + (size_t)4096 * 4096;        // 4096x6144 fused Q|K|V
  u16* vT     = qkv   + (size_t)4096 * 6144;        // 1024x4096 (NKV*HD, B*S)
  u16* attn   = xb;                                 // xb dead after QKV gemm

  cast_f2b<<<2048, 256, 0, stream>>>(x, xb, 4096 * 4096 / 4);
  transpose_cast<<<dim3(128, 128), dim3(32, 8), 0, stream>>>(wq, wqkvT, 4096, 4096, QSCALE_F);
  transpose_cast<<<dim3(32, 128),  dim3(32, 8), 0, stream>>>(wk, wqkvT + (size_t)4096 * 4096, 4096, 1024, 1.0f);
  transpose_cast<<<dim3(32, 128),  dim3(32, 8), 0, stream>>>(wv, wqkvT + (size_t)5120 * 4096, 4096, 1024, 1.0f);
  transpose_cast<<<dim3(128, 128), dim3(32, 8), 0, stream>>>(wo, woT, 4096, 4096, 1.0f);

  // [q|k|v] = x @ [wq*s | wk | wv]  (fused, N=6144, grid 384 = 1.5 CU-waves)
  gemm256<1><<<384, 512, 0, stream>>>(xb, wqkvT, qkv, 4096, 6144, 4096, 24);
  // vT = transpose of the V panel (rows stride 6144)
  transpose_u16<<<dim3(32, 128), dim3(32, 8), 0, stream>>>(qkv + 5120, vT, 4096, 1024, 6144, 4096);

  attn_fwd<<<dim3(8, 32, 2), 512, 0, stream>>>(qkv, vT, attn);

  gemm256<0><<<256, 512, 0, stream>>>(attn, woT, out, 4096, 4096, 4096, 16);
}